// Round 4
// baseline (913.450 us; speedup 1.0000x reference)
//
#include <hip/hip_runtime.h>

#define N_ 100000
#define E_ 1600000
#define HD 128

typedef unsigned short u16;
typedef unsigned int u32;
typedef __bf16 bf16x8 __attribute__((ext_vector_type(8)));
typedef float f32x4 __attribute__((ext_vector_type(4)));

// packed-weight element counts / offsets (in u16 elements)
#define OFF_W2 0
#define OFF_W3 16384
#define OFF_WL 32768
#define OFF_P2 49152
#define OFF_P1 65536
#define PK_TOT 98304   // hi plane size; lo plane at +PK_TOT

__device__ __forceinline__ u16 f2bf(float f) {
    u32 u = __float_as_uint(f);
    return (u16)((u + 0x7FFFu + ((u >> 16) & 1u)) >> 16);
}
__device__ __forceinline__ float bf2f(u16 h) {
    return __uint_as_float(((u32)h) << 16);
}
__device__ __forceinline__ f32x4 mfma16(uint4 a, uint4 b, f32x4 c) {
    return __builtin_amdgcn_mfma_f32_16x16x32_bf16(
        __builtin_bit_cast(bf16x8, a), __builtin_bit_cast(bf16x8, b), c, 0, 0, 0);
}

// Activation LDS layout (u16 array, [rows][128]): idx = row*128 + (col ^ ((row&7)<<3))
// A-fragment (mfma_f32_16x16x32_bf16): lane l holds A[row=l&15][k=8*(l>>4)+j], j=0..7
__device__ __forceinline__ uint4 ldsA(const u16* A, int row, int kt, int l) {
    int idx = row * 128 + (((kt * 32 + ((l >> 4) << 3))) ^ ((row & 7) << 3));
    return *(const uint4*)&A[idx];
}

// write C fragment (col=l&15 (+16*nt), row=4*(l>>4)+r (+16*mt)) as ReLU'd hi/lo bf16
__device__ __forceinline__ void writeAct(u16* Ah, u16* Al, f32x4 acc, int mt, int nt, int l) {
    const int col = nt * 16 + (l & 15);
#pragma unroll
    for (int r = 0; r < 4; ++r) {
        const int row = mt * 16 + ((l >> 4) << 2) + r;
        float a = fmaxf(acc[r], 0.f);
        u16 h = f2bf(a);
        const int idx = row * 128 + (col ^ ((row & 7) << 3));
        Ah[idx] = h;
        Al[idx] = f2bf(a - bf2f(h));
    }
}

// One MFMA layer: C[MT*16 x 128] = relu-pending( A[MT*16 x KT*32] @ W + bias )
// Wave w owns n-tiles 2w, 2w+1. hi/lo split: C += Ah*Bh + Ah*Bl + Al*Bh.
template<int MT, int KT>
__device__ __forceinline__ void mfmaLayer(const u16* Ah, const u16* Al,
                                          const u16* __restrict__ wph,
                                          const u16* __restrict__ wpl,
                                          const float* __restrict__ bias,
                                          int w, int l, f32x4 acc[MT][2])
{
    const int col0 = 2 * w * 16 + (l & 15);
#pragma unroll
    for (int mt = 0; mt < MT; ++mt)
#pragma unroll
        for (int nti = 0; nti < 2; ++nti) {
            float bv = bias[col0 + nti * 16];
            acc[mt][nti][0] = bv; acc[mt][nti][1] = bv;
            acc[mt][nti][2] = bv; acc[mt][nti][3] = bv;
        }
#pragma unroll
    for (int kt = 0; kt < KT; ++kt) {
        uint4 ah[MT], al[MT];
#pragma unroll
        for (int mt = 0; mt < MT; ++mt) {
            ah[mt] = ldsA(Ah, mt * 16 + (l & 15), kt, l);
            al[mt] = ldsA(Al, mt * 16 + (l & 15), kt, l);
        }
#pragma unroll
        for (int nti = 0; nti < 2; ++nti) {
            const int nt = 2 * w + nti;
            uint4 bh = *(const uint4*)&wph[((nt * KT + kt) * 64 + l) * 8];
            uint4 bl = *(const uint4*)&wpl[((nt * KT + kt) * 64 + l) * 8];
#pragma unroll
            for (int mt = 0; mt < MT; ++mt) {
                acc[mt][nti] = mfma16(ah[mt], bh, acc[mt][nti]);
                acc[mt][nti] = mfma16(ah[mt], bl, acc[mt][nti]);
                acc[mt][nti] = mfma16(al[mt], bh, acc[mt][nti]);
            }
        }
    }
}

// ---------------------------------------------------------------------------
// Weight pre-pack: fragment-ordered bf16 hi/lo planes.
// ---------------------------------------------------------------------------
__global__ __launch_bounds__(256) void k_pack(
    const float* __restrict__ W2, const float* __restrict__ W3,
    const float* __restrict__ Wl, const float* __restrict__ P2,
    const float* __restrict__ P1, u16* __restrict__ wpk)
{
    int e = blockIdx.x * 256 + threadIdx.x;
    if (e >= PK_TOT) return;
    const float* src; int local, KT;
    if (e < OFF_P1) {
        int m = e >> 14;
        src = (m == 0) ? W2 : (m == 1) ? W3 : (m == 2) ? Wl : P2;
        local = e & 16383; KT = 4;
    } else {
        src = P1; local = e - OFF_P1; KT = 8;
    }
    int j = local & 7, lane = (local >> 3) & 63, t = local >> 9;
    int kt = t % KT, nt = t / KT;
    int k = kt * 32 + ((lane >> 4) << 3) + j;
    int n = nt * 16 + (lane & 15);
    float v = src[k * HD + n];
    u16 h = f2bf(v);
    wpk[e] = h;
    wpk[PK_TOT + e] = f2bf(v - bf2f(h));
}

// ---------------------------------------------------------------------------
// layer1 (16 -> 128) VALU fp32, output as hi/lo bf16 into U. NPH nodes/thread.
// ---------------------------------------------------------------------------
template<int NPH>
__device__ __forceinline__ void layer1(const float xs[][16],
                                       const float* __restrict__ W1,
                                       const float* __restrict__ b1,
                                       u16* Uh, u16* Ul, int f, int g)
{
    float w[16];
#pragma unroll
    for (int j = 0; j < 16; ++j) w[j] = W1[j * HD + f];
    const float bb = b1[f];
#pragma unroll
    for (int nn = 0; nn < NPH; ++nn) {
        const int row = g * NPH + nn;
        const float4* h4 = (const float4*)xs[row];
        float4 h0 = h4[0], h1 = h4[1], h2 = h4[2], h3 = h4[3];
        float a = bb
            + h0.x * w[0] + h0.y * w[1] + h0.z * w[2] + h0.w * w[3]
            + h1.x * w[4] + h1.y * w[5] + h1.z * w[6] + h1.w * w[7]
            + h2.x * w[8] + h2.y * w[9] + h2.z * w[10] + h2.w * w[11]
            + h3.x * w[12] + h3.y * w[13] + h3.z * w[14] + h3.w * w[15];
        a = fmaxf(a, 0.f);
        u16 h = f2bf(a);
        const int idx = row * 128 + (f ^ ((row & 7) << 3));
        Uh[idx] = h;
        Ul[idx] = f2bf(a - bf2f(h));
    }
}

// ---------------------------------------------------------------------------
// K1: mlp_pre + lin -> msg16[N,128] (bf16).  32 nodes / 256-thread block.
// ---------------------------------------------------------------------------
__global__ __launch_bounds__(256) void k_msg(
    const float* __restrict__ x,
    const float* __restrict__ W1, const float* __restrict__ b1,
    const float* __restrict__ b2, const float* __restrict__ b3,
    const float* __restrict__ bl,
    const u16* __restrict__ wpk, u16* __restrict__ msg16)
{
    __shared__ float xs[32][16];
    __shared__ __align__(16) u16 Uh[4096], Ul[4096], Vh[4096], Vl[4096];
    const int tid = threadIdx.x;
    const int l = tid & 63, w = tid >> 6;
    const int base = blockIdx.x * 32;

    for (int i = tid; i < 32 * 16; i += 256)
        xs[i >> 4][i & 15] = x[(base + (i >> 4)) * 16 + (i & 15)];
    __syncthreads();

    layer1<16>(xs, W1, b1, Uh, Ul, tid & 127, tid >> 7);
    __syncthreads();

    f32x4 acc[2][2];
    // W2: U -> V
    mfmaLayer<2, 4>(Uh, Ul, wpk + OFF_W2, wpk + PK_TOT + OFF_W2, b2, w, l, acc);
#pragma unroll
    for (int mt = 0; mt < 2; ++mt)
#pragma unroll
        for (int nti = 0; nti < 2; ++nti) writeAct(Vh, Vl, acc[mt][nti], mt, 2 * w + nti, l);
    __syncthreads();

    // W3: V -> U
    mfmaLayer<2, 4>(Vh, Vl, wpk + OFF_W3, wpk + PK_TOT + OFF_W3, b3, w, l, acc);
#pragma unroll
    for (int mt = 0; mt < 2; ++mt)
#pragma unroll
        for (int nti = 0; nti < 2; ++nti) writeAct(Uh, Ul, acc[mt][nti], mt, 2 * w + nti, l);
    __syncthreads();

    // lin: U -> V (hi plane = bf16(msg))
    mfmaLayer<2, 4>(Uh, Ul, wpk + OFF_WL, wpk + PK_TOT + OFF_WL, bl, w, l, acc);
#pragma unroll
    for (int mt = 0; mt < 2; ++mt)
#pragma unroll
        for (int nti = 0; nti < 2; ++nti) writeAct(Vh, Vl, acc[mt][nti], mt, 2 * w + nti, l);
    __syncthreads();

    // coalesced copy of hi plane -> msg16 (contiguous dwordx4 stores)
#pragma unroll
    for (int chunk = 0; chunk < 2; ++chunk) {
        int e = tid * 8 + chunk * 2048;
        int r = e >> 7, c0 = e & 127;
        uint4 v = *(const uint4*)&Vh[r * HD + (c0 ^ ((r & 7) << 3))];
        *(uint4*)&msg16[(size_t)(base + r) * HD + c0] = v;
    }
}

// ---------------------------------------------------------------------------
// CSR build (unchanged)
// ---------------------------------------------------------------------------
__global__ void k_hist(const int* __restrict__ dst, int* __restrict__ deg)
{
    int e = blockIdx.x * 256 + threadIdx.x;
    if (e < E_) atomicAdd(&deg[dst[e]], 1);
}

__global__ void k_bsum(const int* __restrict__ deg, int* __restrict__ part)
{
    __shared__ int s[256];
    int i = blockIdx.x * 256 + threadIdx.x;
    int t = threadIdx.x;
    s[t] = (i < N_) ? deg[i] : 0;
    __syncthreads();
    for (int st = 128; st > 0; st >>= 1) {
        if (t < st) s[t] += s[t + st];
        __syncthreads();
    }
    if (t == 0) part[blockIdx.x] = s[0];
}

__global__ void k_pscan(const int* __restrict__ part, int* __restrict__ poff, int nb)
{
    __shared__ int s[512];
    int t = threadIdx.x;
    int d = (t < nb) ? part[t] : 0;
    s[t] = d;
    __syncthreads();
    for (int st = 1; st < 512; st <<= 1) {
        int v = (t >= st) ? s[t - st] : 0;
        __syncthreads();
        s[t] += v;
        __syncthreads();
    }
    if (t < nb) poff[t] = s[t] - d;
}

__global__ void k_scan(const int* __restrict__ deg, const int* __restrict__ poff,
                       int* __restrict__ offs, int* __restrict__ cursor)
{
    __shared__ int s[256];
    int i = blockIdx.x * 256 + threadIdx.x;
    int t = threadIdx.x;
    int d = (i < N_) ? deg[i] : 0;
    s[t] = d;
    __syncthreads();
    for (int st = 1; st < 256; st <<= 1) {
        int v = (t >= st) ? s[t - st] : 0;
        __syncthreads();
        s[t] += v;
        __syncthreads();
    }
    if (i < N_) {
        int ex = s[t] - d + poff[blockIdx.x];
        offs[i] = ex;
        cursor[i] = ex;
    }
}

__global__ void k_fill(const int* __restrict__ src, const int* __restrict__ dst,
                       int* __restrict__ cursor, int* __restrict__ csr)
{
    int e = blockIdx.x * 256 + threadIdx.x;
    if (e < E_) {
        int pos = atomicAdd(&cursor[dst[e]], 1);
        csr[pos] = src[e];
    }
}

// ---------------------------------------------------------------------------
// K3: recompute pre (MFMA) + fused bf16 CSR gather + mlp_post (MFMA) -> out.
// 16 nodes / 256-thread block; LDS 17.4 KB -> 8 blocks/CU (32 waves).
// ---------------------------------------------------------------------------
__global__ __launch_bounds__(256, 8) void k_post(
    const float* __restrict__ x,
    const u16* __restrict__ msg16, const int* __restrict__ csr,
    const int* __restrict__ offs, const int* __restrict__ endp,
    const float* __restrict__ W1, const float* __restrict__ b1,
    const float* __restrict__ b2, const float* __restrict__ b3,
    const float* __restrict__ pb1, const float* __restrict__ pb2,
    const float* __restrict__ P3, const float* __restrict__ pb3,
    const u16* __restrict__ wpk, float* __restrict__ out)
{
    __shared__ float xs[16][16];
    __shared__ __align__(16) u16 Uh[2048], Ul[2048], Vh[2048], Vl[2048];
    const int tid = threadIdx.x;
    const int l = tid & 63, w = tid >> 6;
    const int base = blockIdx.x * 16;

    xs[tid >> 4][tid & 15] = x[(base + (tid >> 4)) * 16 + (tid & 15)];
    __syncthreads();

    layer1<8>(xs, W1, b1, Uh, Ul, tid & 127, tid >> 7);
    __syncthreads();

    f32x4 acc[1][2];
    // W2: U -> V (h2)
    mfmaLayer<1, 4>(Uh, Ul, wpk + OFF_W2, wpk + PK_TOT + OFF_W2, b2, w, l, acc);
#pragma unroll
    for (int nti = 0; nti < 2; ++nti) writeAct(Vh, Vl, acc[0][nti], 0, 2 * w + nti, l);
    __syncthreads();

    // W3: V -> U (pre)
    mfmaLayer<1, 4>(Vh, Vl, wpk + OFF_W3, wpk + PK_TOT + OFF_W3, b3, w, l, acc);
#pragma unroll
    for (int nti = 0; nti < 2; ++nti) writeAct(Uh, Ul, acc[0][nti], 0, 2 * w + nti, l);
    __syncthreads();   // U = pre; V free

    // ---- gather (bf16 msg): lane covers cols 4c..4c+3; half h handles
    // edges i+h; combine halves with shfl_xor(32). Writes agg into V hi/lo. ----
    {
        const int c = l & 31, h = l >> 5;
        for (int j = 0; j < 4; ++j) {
            const int n = w * 4 + j;
            const int node = base + n;
            const int s = offs[node], e = endp[node];
            float a0 = 0.f, a1 = 0.f, a2 = 0.f, a3 = 0.f;
            int i = s;
            for (; i + 2 <= e; i += 2) {
                int src = csr[i + h];
                const u32* row = (const u32*)(msg16 + (size_t)src * HD);
                uint2 d = *(const uint2*)&row[2 * c];
                a0 += __uint_as_float(d.x << 16);
                a1 += __uint_as_float(d.x & 0xffff0000u);
                a2 += __uint_as_float(d.y << 16);
                a3 += __uint_as_float(d.y & 0xffff0000u);
            }
            if (i < e && h == 0) {
                int src = csr[i];
                const u32* row = (const u32*)(msg16 + (size_t)src * HD);
                uint2 d = *(const uint2*)&row[2 * c];
                a0 += __uint_as_float(d.x << 16);
                a1 += __uint_as_float(d.x & 0xffff0000u);
                a2 += __uint_as_float(d.y << 16);
                a3 += __uint_as_float(d.y & 0xffff0000u);
            }
            a0 += __shfl_xor(a0, 32);
            a1 += __shfl_xor(a1, 32);
            a2 += __shfl_xor(a2, 32);
            a3 += __shfl_xor(a3, 32);
            if (h == 0) {
                const int idx = n * HD + ((4 * c) ^ ((n & 7) << 3));
                float av[4] = {a0, a1, a2, a3};
#pragma unroll
                for (int q = 0; q < 4; ++q) {
                    u16 hi = f2bf(av[q]);
                    Vh[idx + q] = hi;
                    Vl[idx + q] = f2bf(av[q] - bf2f(hi));
                }
            }
        }
    }
    __syncthreads();   // V = agg

    // P1: K=256 -> kt 0-3 read U (pre), kt 4-7 read V (agg)
    {
        const int col0 = 2 * w * 16 + (l & 15);
#pragma unroll
        for (int nti = 0; nti < 2; ++nti) {
            float bv = pb1[col0 + nti * 16];
            acc[0][nti][0] = bv; acc[0][nti][1] = bv;
            acc[0][nti][2] = bv; acc[0][nti][3] = bv;
        }
#pragma unroll
        for (int kt = 0; kt < 8; ++kt) {
            const u16* sh = (kt < 4) ? Uh : Vh;
            const u16* sl = (kt < 4) ? Ul : Vl;
            uint4 ah = ldsA(sh, l & 15, kt & 3, l);
            uint4 al = ldsA(sl, l & 15, kt & 3, l);
#pragma unroll
            for (int nti = 0; nti < 2; ++nti) {
                const int nt = 2 * w + nti;
                uint4 bh = *(const uint4*)&wpk[OFF_P1 + ((nt * 8 + kt) * 64 + l) * 8];
                uint4 bl = *(const uint4*)&wpk[PK_TOT + OFF_P1 + ((nt * 8 + kt) * 64 + l) * 8];
                acc[0][nti] = mfma16(ah, bh, acc[0][nti]);
                acc[0][nti] = mfma16(ah, bl, acc[0][nti]);
                acc[0][nti] = mfma16(al, bh, acc[0][nti]);
            }
        }
    }
    __syncthreads();   // all reads of U,V done
#pragma unroll
    for (int nti = 0; nti < 2; ++nti) writeAct(Uh, Ul, acc[0][nti], 0, 2 * w + nti, l);
    __syncthreads();

    // P2: U -> V (hi/lo, ReLU'd)
    mfmaLayer<1, 4>(Uh, Ul, wpk + OFF_P2, wpk + PK_TOT + OFF_P2, pb2, w, l, acc);
#pragma unroll
    for (int nti = 0; nti < 2; ++nti) writeAct(Vh, Vl, acc[0][nti], 0, 2 * w + nti, l);
    __syncthreads();

    // P3: 128 -> 16 + outer ReLU (VALU fp32, reads V hi+lo)
    {
        const int o = tid & 15;
        const int n = tid >> 4;
        const int sn = (n & 7) << 3;
        float a = pb3[o];
        for (int k0 = 0; k0 < HD; k0 += 8) {
            uint4 ph = *(const uint4*)&Vh[n * HD + (k0 ^ sn)];
            uint4 pl = *(const uint4*)&Vl[n * HD + (k0 ^ sn)];
            const u32 pw[4] = {ph.x, ph.y, ph.z, ph.w};
            const u32 qw[4] = {pl.x, pl.y, pl.z, pl.w};
#pragma unroll
            for (int j = 0; j < 8; ++j) {
                u32 hv = (j & 1) ? (pw[j >> 1] & 0xffff0000u) : (pw[j >> 1] << 16);
                u32 lv = (j & 1) ? (qw[j >> 1] & 0xffff0000u) : (qw[j >> 1] << 16);
                float hval = __uint_as_float(hv) + __uint_as_float(lv);
                a += hval * P3[(k0 + j) * 16 + o];
            }
        }
        out[(size_t)(base + n) * 16 + o] = fmaxf(a, 0.f);
    }
}

// ---------------------------------------------------------------------------
extern "C" void kernel_launch(void* const* d_in, const int* in_sizes, int n_in,
                              void* d_out, int out_size, void* d_ws, size_t ws_size,
                              hipStream_t stream)
{
    const float* x  = (const float*)d_in[0];
    const int*   ei = (const int*)d_in[1];
    const float* W1 = (const float*)d_in[2];  const float* b1  = (const float*)d_in[3];
    const float* W2 = (const float*)d_in[4];  const float* b2  = (const float*)d_in[5];
    const float* W3 = (const float*)d_in[6];  const float* b3  = (const float*)d_in[7];
    const float* Wl = (const float*)d_in[8];  const float* bl  = (const float*)d_in[9];
    const float* P1 = (const float*)d_in[10]; const float* pb1 = (const float*)d_in[11];
    const float* P2 = (const float*)d_in[12]; const float* pb2 = (const float*)d_in[13];
    const float* P3 = (const float*)d_in[14]; const float* pb3 = (const float*)d_in[15];
    float* out = (float*)d_out;

    // Workspace: msg16 25.6 MB + csr 6.4 MB + ints 1.2 MB + wpk 0.4 MB ~= 34 MB
    char* ws = (char*)d_ws;
    u16* msg16  = (u16*)ws;   ws += (size_t)N_ * HD * 2;
    int* csr    = (int*)ws;   ws += (size_t)E_ * 4;
    int* deg    = (int*)ws;   ws += (size_t)N_ * 4;
    int* offs   = (int*)ws;   ws += (size_t)N_ * 4;
    int* cursor = (int*)ws;   ws += (size_t)N_ * 4;
    int* part   = (int*)ws;   ws += 512 * 4;
    int* poff   = (int*)ws;   ws += 512 * 4;
    u16* wpk    = (u16*)ws;   ws += (size_t)2 * PK_TOT * 2;

    const int* srcv = ei;
    const int* dstv = ei + E_;

    const int nbN = (N_ + 255) / 256;   // 391
    const int nbE = (E_ + 255) / 256;

    hipMemsetAsync(deg, 0, (size_t)N_ * 4, stream);
    k_pack<<<(PK_TOT + 255) / 256, 256, 0, stream>>>(W2, W3, Wl, P2, P1, wpk);
    k_msg<<<N_ / 32, 256, 0, stream>>>(x, W1, b1, b2, b3, bl, wpk, msg16);
    k_hist<<<nbE, 256, 0, stream>>>(dstv, deg);
    k_bsum<<<nbN, 256, 0, stream>>>(deg, part);
    k_pscan<<<1, 512, 0, stream>>>(part, poff, nbN);
    k_scan<<<nbN, 256, 0, stream>>>(deg, poff, offs, cursor);
    k_fill<<<nbE, 256, 0, stream>>>(srcv, dstv, cursor, csr);
    k_post<<<N_ / 16, 256, 0, stream>>>(x, msg16, csr, offs, cursor,
                                        W1, b1, b2, b3, pb1, pb2, P3, pb3,
                                        wpk, out);
}

// Round 5
// 605.520 us; speedup vs baseline: 1.5085x; 1.5085x over previous
//
#include <hip/hip_runtime.h>

#define N_ 100000
#define E_ 1600000
#define HD 128

typedef unsigned short u16;
typedef unsigned int u32;
typedef __bf16 bf16x8 __attribute__((ext_vector_type(8)));
typedef float f32x4 __attribute__((ext_vector_type(4)));

// packed-weight element counts / offsets (in u16 elements)
#define OFF_W2 0
#define OFF_W3 16384
#define OFF_WL 32768
#define OFF_P2 49152
#define OFF_P1 65536
#define PK_TOT 98304   // hi plane size; lo plane at +PK_TOT

__device__ __forceinline__ u16 f2bf(float f) {
    u32 u = __float_as_uint(f);
    return (u16)((u + 0x7FFFu + ((u >> 16) & 1u)) >> 16);
}
__device__ __forceinline__ float bf2f(u16 h) {
    return __uint_as_float(((u32)h) << 16);
}
__device__ __forceinline__ f32x4 mfma16(uint4 a, uint4 b, f32x4 c) {
    return __builtin_amdgcn_mfma_f32_16x16x32_bf16(
        __builtin_bit_cast(bf16x8, a), __builtin_bit_cast(bf16x8, b), c, 0, 0, 0);
}

// Activation LDS layout (u16 array, [rows][128]): idx = row*128 + (col ^ ((row&7)<<3))
// A-fragment (mfma_f32_16x16x32_bf16): lane l holds A[row=l&15][k=8*(l>>4)+j], j=0..7
__device__ __forceinline__ uint4 ldsA(const u16* A, int row, int kt, int l) {
    int idx = row * 128 + (((kt * 32 + ((l >> 4) << 3))) ^ ((row & 7) << 3));
    return *(const uint4*)&A[idx];
}

// write C fragment (col=l&15 (+16*nt), row=4*(l>>4)+r (+16*mt)) as ReLU'd hi/lo bf16
__device__ __forceinline__ void writeAct(u16* Ah, u16* Al, f32x4 acc, int mt, int nt, int l) {
    const int col = nt * 16 + (l & 15);
#pragma unroll
    for (int r = 0; r < 4; ++r) {
        const int row = mt * 16 + ((l >> 4) << 2) + r;
        float a = fmaxf(acc[r], 0.f);
        u16 h = f2bf(a);
        const int idx = row * 128 + (col ^ ((row & 7) << 3));
        Ah[idx] = h;
        Al[idx] = f2bf(a - bf2f(h));
    }
}

// One MFMA layer: C[MT*16 x 128] = relu-pending( A[MT*16 x KT*32] @ W + bias )
// Wave w owns n-tiles 2w, 2w+1. hi/lo split: C += Ah*Bh + Ah*Bl + Al*Bh.
template<int MT, int KT>
__device__ __forceinline__ void mfmaLayer(const u16* Ah, const u16* Al,
                                          const u16* __restrict__ wph,
                                          const u16* __restrict__ wpl,
                                          const float* __restrict__ bias,
                                          int w, int l, f32x4 acc[MT][2])
{
    const int col0 = 2 * w * 16 + (l & 15);
#pragma unroll
    for (int mt = 0; mt < MT; ++mt)
#pragma unroll
        for (int nti = 0; nti < 2; ++nti) {
            float bv = bias[col0 + nti * 16];
            acc[mt][nti][0] = bv; acc[mt][nti][1] = bv;
            acc[mt][nti][2] = bv; acc[mt][nti][3] = bv;
        }
#pragma unroll
    for (int kt = 0; kt < KT; ++kt) {
        uint4 ah[MT], al[MT];
#pragma unroll
        for (int mt = 0; mt < MT; ++mt) {
            ah[mt] = ldsA(Ah, mt * 16 + (l & 15), kt, l);
            al[mt] = ldsA(Al, mt * 16 + (l & 15), kt, l);
        }
#pragma unroll
        for (int nti = 0; nti < 2; ++nti) {
            const int nt = 2 * w + nti;
            uint4 bh = *(const uint4*)&wph[((nt * KT + kt) * 64 + l) * 8];
            uint4 bl = *(const uint4*)&wpl[((nt * KT + kt) * 64 + l) * 8];
#pragma unroll
            for (int mt = 0; mt < MT; ++mt) {
                acc[mt][nti] = mfma16(ah[mt], bh, acc[mt][nti]);
                acc[mt][nti] = mfma16(ah[mt], bl, acc[mt][nti]);
                acc[mt][nti] = mfma16(al[mt], bh, acc[mt][nti]);
            }
        }
    }
}

// ---------------------------------------------------------------------------
// Weight pre-pack: fragment-ordered bf16 hi/lo planes.
// ---------------------------------------------------------------------------
__global__ __launch_bounds__(256) void k_pack(
    const float* __restrict__ W2, const float* __restrict__ W3,
    const float* __restrict__ Wl, const float* __restrict__ P2,
    const float* __restrict__ P1, u16* __restrict__ wpk)
{
    int e = blockIdx.x * 256 + threadIdx.x;
    if (e >= PK_TOT) return;
    const float* src; int local, KT;
    if (e < OFF_P1) {
        int m = e >> 14;
        src = (m == 0) ? W2 : (m == 1) ? W3 : (m == 2) ? Wl : P2;
        local = e & 16383; KT = 4;
    } else {
        src = P1; local = e - OFF_P1; KT = 8;
    }
    int j = local & 7, lane = (local >> 3) & 63, t = local >> 9;
    int kt = t % KT, nt = t / KT;
    int k = kt * 32 + ((lane >> 4) << 3) + j;
    int n = nt * 16 + (lane & 15);
    float v = src[k * HD + n];
    u16 h = f2bf(v);
    wpk[e] = h;
    wpk[PK_TOT + e] = f2bf(v - bf2f(h));
}

// ---------------------------------------------------------------------------
// layer1 (16 -> 128) VALU fp32, output as hi/lo bf16 into U. NPH nodes/thread.
// ---------------------------------------------------------------------------
template<int NPH>
__device__ __forceinline__ void layer1(const float xs[][16],
                                       const float* __restrict__ W1,
                                       const float* __restrict__ b1,
                                       u16* Uh, u16* Ul, int f, int g)
{
    float w[16];
#pragma unroll
    for (int j = 0; j < 16; ++j) w[j] = W1[j * HD + f];
    const float bb = b1[f];
#pragma unroll
    for (int nn = 0; nn < NPH; ++nn) {
        const int row = g * NPH + nn;
        const float4* h4 = (const float4*)xs[row];
        float4 h0 = h4[0], h1 = h4[1], h2 = h4[2], h3 = h4[3];
        float a = bb
            + h0.x * w[0] + h0.y * w[1] + h0.z * w[2] + h0.w * w[3]
            + h1.x * w[4] + h1.y * w[5] + h1.z * w[6] + h1.w * w[7]
            + h2.x * w[8] + h2.y * w[9] + h2.z * w[10] + h2.w * w[11]
            + h3.x * w[12] + h3.y * w[13] + h3.z * w[14] + h3.w * w[15];
        a = fmaxf(a, 0.f);
        u16 h = f2bf(a);
        const int idx = row * 128 + (f ^ ((row & 7) << 3));
        Uh[idx] = h;
        Ul[idx] = f2bf(a - bf2f(h));
    }
}

// ---------------------------------------------------------------------------
// K1: mlp_pre + lin -> msg16[N,128] (bf16).  32 nodes / 256-thread block.
// ---------------------------------------------------------------------------
__global__ __launch_bounds__(256) void k_msg(
    const float* __restrict__ x,
    const float* __restrict__ W1, const float* __restrict__ b1,
    const float* __restrict__ b2, const float* __restrict__ b3,
    const float* __restrict__ bl,
    const u16* __restrict__ wpk, u16* __restrict__ msg16)
{
    __shared__ float xs[32][16];
    __shared__ __align__(16) u16 Uh[4096], Ul[4096], Vh[4096], Vl[4096];
    const int tid = threadIdx.x;
    const int l = tid & 63, w = tid >> 6;
    const int base = blockIdx.x * 32;

    for (int i = tid; i < 32 * 16; i += 256)
        xs[i >> 4][i & 15] = x[(base + (i >> 4)) * 16 + (i & 15)];
    __syncthreads();

    layer1<16>(xs, W1, b1, Uh, Ul, tid & 127, tid >> 7);
    __syncthreads();

    f32x4 acc[2][2];
    // W2: U -> V
    mfmaLayer<2, 4>(Uh, Ul, wpk + OFF_W2, wpk + PK_TOT + OFF_W2, b2, w, l, acc);
#pragma unroll
    for (int mt = 0; mt < 2; ++mt)
#pragma unroll
        for (int nti = 0; nti < 2; ++nti) writeAct(Vh, Vl, acc[mt][nti], mt, 2 * w + nti, l);
    __syncthreads();

    // W3: V -> U
    mfmaLayer<2, 4>(Vh, Vl, wpk + OFF_W3, wpk + PK_TOT + OFF_W3, b3, w, l, acc);
#pragma unroll
    for (int mt = 0; mt < 2; ++mt)
#pragma unroll
        for (int nti = 0; nti < 2; ++nti) writeAct(Uh, Ul, acc[mt][nti], mt, 2 * w + nti, l);
    __syncthreads();

    // lin: U -> V (hi plane = bf16(msg))
    mfmaLayer<2, 4>(Uh, Ul, wpk + OFF_WL, wpk + PK_TOT + OFF_WL, bl, w, l, acc);
#pragma unroll
    for (int mt = 0; mt < 2; ++mt)
#pragma unroll
        for (int nti = 0; nti < 2; ++nti) writeAct(Vh, Vl, acc[mt][nti], mt, 2 * w + nti, l);
    __syncthreads();

    // coalesced copy of hi plane -> msg16 (contiguous dwordx4 stores)
#pragma unroll
    for (int chunk = 0; chunk < 2; ++chunk) {
        int e = tid * 8 + chunk * 2048;
        int r = e >> 7, c0 = e & 127;
        uint4 v = *(const uint4*)&Vh[r * HD + (c0 ^ ((r & 7) << 3))];
        *(uint4*)&msg16[(size_t)(base + r) * HD + c0] = v;
    }
}

// ---------------------------------------------------------------------------
// CSR build (unchanged)
// ---------------------------------------------------------------------------
__global__ void k_hist(const int* __restrict__ dst, int* __restrict__ deg)
{
    int e = blockIdx.x * 256 + threadIdx.x;
    if (e < E_) atomicAdd(&deg[dst[e]], 1);
}

__global__ void k_bsum(const int* __restrict__ deg, int* __restrict__ part)
{
    __shared__ int s[256];
    int i = blockIdx.x * 256 + threadIdx.x;
    int t = threadIdx.x;
    s[t] = (i < N_) ? deg[i] : 0;
    __syncthreads();
    for (int st = 128; st > 0; st >>= 1) {
        if (t < st) s[t] += s[t + st];
        __syncthreads();
    }
    if (t == 0) part[blockIdx.x] = s[0];
}

__global__ void k_pscan(const int* __restrict__ part, int* __restrict__ poff, int nb)
{
    __shared__ int s[512];
    int t = threadIdx.x;
    int d = (t < nb) ? part[t] : 0;
    s[t] = d;
    __syncthreads();
    for (int st = 1; st < 512; st <<= 1) {
        int v = (t >= st) ? s[t - st] : 0;
        __syncthreads();
        s[t] += v;
        __syncthreads();
    }
    if (t < nb) poff[t] = s[t] - d;
}

__global__ void k_scan(const int* __restrict__ deg, const int* __restrict__ poff,
                       int* __restrict__ offs, int* __restrict__ cursor)
{
    __shared__ int s[256];
    int i = blockIdx.x * 256 + threadIdx.x;
    int t = threadIdx.x;
    int d = (i < N_) ? deg[i] : 0;
    s[t] = d;
    __syncthreads();
    for (int st = 1; st < 256; st <<= 1) {
        int v = (t >= st) ? s[t - st] : 0;
        __syncthreads();
        s[t] += v;
        __syncthreads();
    }
    if (i < N_) {
        int ex = s[t] - d + poff[blockIdx.x];
        offs[i] = ex;
        cursor[i] = ex;
    }
}

__global__ void k_fill(const int* __restrict__ src, const int* __restrict__ dst,
                       int* __restrict__ cursor, int* __restrict__ csr)
{
    int e = blockIdx.x * 256 + threadIdx.x;
    if (e < E_) {
        int pos = atomicAdd(&cursor[dst[e]], 1);
        csr[pos] = src[e];
    }
}

// ---------------------------------------------------------------------------
// K3: recompute pre (MFMA) + fused bf16 CSR gather + mlp_post (MFMA) -> out.
// 16 nodes / 256-thread block; LDS 17.4 KB.
// __launch_bounds__(256,4): 128-VGPR cap — (256,8) forced a 64-reg budget and
// spilled ~1 GB of scratch traffic (round 4); never cap below the kernel's need.
// ---------------------------------------------------------------------------
__global__ __launch_bounds__(256, 4) void k_post(
    const float* __restrict__ x,
    const u16* __restrict__ msg16, const int* __restrict__ csr,
    const int* __restrict__ offs, const int* __restrict__ endp,
    const float* __restrict__ W1, const float* __restrict__ b1,
    const float* __restrict__ b2, const float* __restrict__ b3,
    const float* __restrict__ pb1, const float* __restrict__ pb2,
    const float* __restrict__ P3, const float* __restrict__ pb3,
    const u16* __restrict__ wpk, float* __restrict__ out)
{
    __shared__ float xs[16][16];
    __shared__ __align__(16) u16 Uh[2048], Ul[2048], Vh[2048], Vl[2048];
    const int tid = threadIdx.x;
    const int l = tid & 63, w = tid >> 6;
    const int base = blockIdx.x * 16;

    xs[tid >> 4][tid & 15] = x[(base + (tid >> 4)) * 16 + (tid & 15)];
    __syncthreads();

    layer1<8>(xs, W1, b1, Uh, Ul, tid & 127, tid >> 7);
    __syncthreads();

    f32x4 acc[1][2];
    // W2: U -> V (h2)
    mfmaLayer<1, 4>(Uh, Ul, wpk + OFF_W2, wpk + PK_TOT + OFF_W2, b2, w, l, acc);
#pragma unroll
    for (int nti = 0; nti < 2; ++nti) writeAct(Vh, Vl, acc[0][nti], 0, 2 * w + nti, l);
    __syncthreads();

    // W3: V -> U (pre)
    mfmaLayer<1, 4>(Vh, Vl, wpk + OFF_W3, wpk + PK_TOT + OFF_W3, b3, w, l, acc);
#pragma unroll
    for (int nti = 0; nti < 2; ++nti) writeAct(Uh, Ul, acc[0][nti], 0, 2 * w + nti, l);
    __syncthreads();   // U = pre; V free

    // ---- gather (bf16 msg): lane covers cols 4c..4c+3; half h handles
    // edges i+h; combine halves with shfl_xor(32). Writes agg into V hi/lo. ----
    {
        const int c = l & 31, h = l >> 5;
        for (int j = 0; j < 4; ++j) {
            const int n = w * 4 + j;
            const int node = base + n;
            const int s = offs[node], e = endp[node];
            float a0 = 0.f, a1 = 0.f, a2 = 0.f, a3 = 0.f;
            int i = s;
            for (; i + 2 <= e; i += 2) {
                int src = csr[i + h];
                const u32* row = (const u32*)(msg16 + (size_t)src * HD);
                uint2 d = *(const uint2*)&row[2 * c];
                a0 += __uint_as_float(d.x << 16);
                a1 += __uint_as_float(d.x & 0xffff0000u);
                a2 += __uint_as_float(d.y << 16);
                a3 += __uint_as_float(d.y & 0xffff0000u);
            }
            if (i < e && h == 0) {
                int src = csr[i];
                const u32* row = (const u32*)(msg16 + (size_t)src * HD);
                uint2 d = *(const uint2*)&row[2 * c];
                a0 += __uint_as_float(d.x << 16);
                a1 += __uint_as_float(d.x & 0xffff0000u);
                a2 += __uint_as_float(d.y << 16);
                a3 += __uint_as_float(d.y & 0xffff0000u);
            }
            a0 += __shfl_xor(a0, 32);
            a1 += __shfl_xor(a1, 32);
            a2 += __shfl_xor(a2, 32);
            a3 += __shfl_xor(a3, 32);
            if (h == 0) {
                const int idx = n * HD + ((4 * c) ^ ((n & 7) << 3));
                float av[4] = {a0, a1, a2, a3};
#pragma unroll
                for (int q = 0; q < 4; ++q) {
                    u16 hi = f2bf(av[q]);
                    Vh[idx + q] = hi;
                    Vl[idx + q] = f2bf(av[q] - bf2f(hi));
                }
            }
        }
    }
    __syncthreads();   // V = agg

    // P1: K=256 -> kt 0-3 read U (pre), kt 4-7 read V (agg)
    {
        const int col0 = 2 * w * 16 + (l & 15);
#pragma unroll
        for (int nti = 0; nti < 2; ++nti) {
            float bv = pb1[col0 + nti * 16];
            acc[0][nti][0] = bv; acc[0][nti][1] = bv;
            acc[0][nti][2] = bv; acc[0][nti][3] = bv;
        }
#pragma unroll
        for (int kt = 0; kt < 8; ++kt) {
            const u16* sh = (kt < 4) ? Uh : Vh;
            const u16* sl = (kt < 4) ? Ul : Vl;
            uint4 ah = ldsA(sh, l & 15, kt & 3, l);
            uint4 al = ldsA(sl, l & 15, kt & 3, l);
#pragma unroll
            for (int nti = 0; nti < 2; ++nti) {
                const int nt = 2 * w + nti;
                uint4 bh = *(const uint4*)&wpk[OFF_P1 + ((nt * 8 + kt) * 64 + l) * 8];
                uint4 bl = *(const uint4*)&wpk[PK_TOT + OFF_P1 + ((nt * 8 + kt) * 64 + l) * 8];
                acc[0][nti] = mfma16(ah, bh, acc[0][nti]);
                acc[0][nti] = mfma16(ah, bl, acc[0][nti]);
                acc[0][nti] = mfma16(al, bh, acc[0][nti]);
            }
        }
    }
    __syncthreads();   // all reads of U,V done
#pragma unroll
    for (int nti = 0; nti < 2; ++nti) writeAct(Uh, Ul, acc[0][nti], 0, 2 * w + nti, l);
    __syncthreads();

    // P2: U -> V (hi/lo, ReLU'd)
    mfmaLayer<1, 4>(Uh, Ul, wpk + OFF_P2, wpk + PK_TOT + OFF_P2, pb2, w, l, acc);
#pragma unroll
    for (int nti = 0; nti < 2; ++nti) writeAct(Vh, Vl, acc[0][nti], 0, 2 * w + nti, l);
    __syncthreads();

    // P3: 128 -> 16 + outer ReLU (VALU fp32, reads V hi+lo)
    {
        const int o = tid & 15;
        const int n = tid >> 4;
        const int sn = (n & 7) << 3;
        float a = pb3[o];
        for (int k0 = 0; k0 < HD; k0 += 8) {
            uint4 ph = *(const uint4*)&Vh[n * HD + (k0 ^ sn)];
            uint4 pl = *(const uint4*)&Vl[n * HD + (k0 ^ sn)];
            const u32 pw[4] = {ph.x, ph.y, ph.z, ph.w};
            const u32 qw[4] = {pl.x, pl.y, pl.z, pl.w};
#pragma unroll
            for (int j = 0; j < 8; ++j) {
                u32 hv = (j & 1) ? (pw[j >> 1] & 0xffff0000u) : (pw[j >> 1] << 16);
                u32 lv = (j & 1) ? (qw[j >> 1] & 0xffff0000u) : (qw[j >> 1] << 16);
                float hval = __uint_as_float(hv) + __uint_as_float(lv);
                a += hval * P3[(k0 + j) * 16 + o];
            }
        }
        out[(size_t)(base + n) * 16 + o] = fmaxf(a, 0.f);
    }
}

// ---------------------------------------------------------------------------
extern "C" void kernel_launch(void* const* d_in, const int* in_sizes, int n_in,
                              void* d_out, int out_size, void* d_ws, size_t ws_size,
                              hipStream_t stream)
{
    const float* x  = (const float*)d_in[0];
    const int*   ei = (const int*)d_in[1];
    const float* W1 = (const float*)d_in[2];  const float* b1  = (const float*)d_in[3];
    const float* W2 = (const float*)d_in[4];  const float* b2  = (const float*)d_in[5];
    const float* W3 = (const float*)d_in[6];  const float* b3  = (const float*)d_in[7];
    const float* Wl = (const float*)d_in[8];  const float* bl  = (const float*)d_in[9];
    const float* P1 = (const float*)d_in[10]; const float* pb1 = (const float*)d_in[11];
    const float* P2 = (const float*)d_in[12]; const float* pb2 = (const float*)d_in[13];
    const float* P3 = (const float*)d_in[14]; const float* pb3 = (const float*)d_in[15];
    float* out = (float*)d_out;

    // Workspace: msg16 25.6 MB + csr 6.4 MB + ints 1.2 MB + wpk 0.4 MB ~= 34 MB
    char* ws = (char*)d_ws;
    u16* msg16  = (u16*)ws;   ws += (size_t)N_ * HD * 2;
    int* csr    = (int*)ws;   ws += (size_t)E_ * 4;
    int* deg    = (int*)ws;   ws += (size_t)N_ * 4;
    int* offs   = (int*)ws;   ws += (size_t)N_ * 4;
    int* cursor = (int*)ws;   ws += (size_t)N_ * 4;
    int* part   = (int*)ws;   ws += 512 * 4;
    int* poff   = (int*)ws;   ws += 512 * 4;
    u16* wpk    = (u16*)ws;   ws += (size_t)2 * PK_TOT * 2;

    const int* srcv = ei;
    const int* dstv = ei + E_;

    const int nbN = (N_ + 255) / 256;   // 391
    const int nbE = (E_ + 255) / 256;

    hipMemsetAsync(deg, 0, (size_t)N_ * 4, stream);
    k_pack<<<(PK_TOT + 255) / 256, 256, 0, stream>>>(W2, W3, Wl, P2, P1, wpk);
    k_msg<<<N_ / 32, 256, 0, stream>>>(x, W1, b1, b2, b3, bl, wpk, msg16);
    k_hist<<<nbE, 256, 0, stream>>>(dstv, deg);
    k_bsum<<<nbN, 256, 0, stream>>>(deg, part);
    k_pscan<<<1, 512, 0, stream>>>(part, poff, nbN);
    k_scan<<<nbN, 256, 0, stream>>>(deg, poff, offs, cursor);
    k_fill<<<nbE, 256, 0, stream>>>(srcv, dstv, cursor, csr);
    k_post<<<N_ / 16, 256, 0, stream>>>(x, msg16, csr, offs, cursor,
                                        W1, b1, b2, b3, pb1, pb2, P3, pb3,
                                        wpk, out);
}

// Round 6
// 478.277 us; speedup vs baseline: 1.9099x; 1.2660x over previous
//
#include <hip/hip_runtime.h>

#define N_ 100000
#define E_ 1600000
#define HD 128

typedef unsigned short u16;
typedef unsigned int u32;
typedef __bf16 bf16x8 __attribute__((ext_vector_type(8)));
typedef float f32x4 __attribute__((ext_vector_type(4)));

// packed-weight element counts / offsets (in u16 elements)
#define OFF_W2 0
#define OFF_W3 16384
#define OFF_WL 32768
#define OFF_P2 49152
#define OFF_P1 65536
#define PK_TOT 98304   // hi plane size; lo plane at +PK_TOT

__device__ __forceinline__ u16 f2bf(float f) {
    u32 u = __float_as_uint(f);
    return (u16)((u + 0x7FFFu + ((u >> 16) & 1u)) >> 16);
}
__device__ __forceinline__ float bf2f(u16 h) {
    return __uint_as_float(((u32)h) << 16);
}
__device__ __forceinline__ f32x4 mfma16(uint4 a, uint4 b, f32x4 c) {
    return __builtin_amdgcn_mfma_f32_16x16x32_bf16(
        __builtin_bit_cast(bf16x8, a), __builtin_bit_cast(bf16x8, b), c, 0, 0, 0);
}

// Activation LDS layout (u16 array, [rows][128]): idx = row*128 + (col ^ ((row&7)<<3))
// A-fragment (mfma_f32_16x16x32_bf16): lane l holds A[row=l&15][k=8*(l>>4)+j], j=0..7
__device__ __forceinline__ uint4 ldsA(const u16* A, int row, int kt, int l) {
    int idx = row * 128 + (((kt * 32 + ((l >> 4) << 3))) ^ ((row & 7) << 3));
    return *(const uint4*)&A[idx];
}

// write C fragment (col=l&15 (+16*nt), row=4*(l>>4)+r (+16*mt)) as ReLU'd hi/lo bf16
__device__ __forceinline__ void writeAct(u16* Ah, u16* Al, f32x4 acc, int mt, int nt, int l) {
    const int col = nt * 16 + (l & 15);
#pragma unroll
    for (int r = 0; r < 4; ++r) {
        const int row = mt * 16 + ((l >> 4) << 2) + r;
        float a = fmaxf(acc[r], 0.f);
        u16 h = f2bf(a);
        const int idx = row * 128 + (col ^ ((row & 7) << 3));
        Ah[idx] = h;
        Al[idx] = f2bf(a - bf2f(h));
    }
}

// One MFMA layer: C[MT*16 x 128] = relu-pending( A[MT*16 x KT*32] @ W + bias )
// Wave w owns n-tiles 2w, 2w+1. hi/lo split: C += Ah*Bh + Ah*Bl + Al*Bh.
template<int MT, int KT>
__device__ __forceinline__ void mfmaLayer(const u16* Ah, const u16* Al,
                                          const u16* __restrict__ wph,
                                          const u16* __restrict__ wpl,
                                          const float* __restrict__ bias,
                                          int w, int l, f32x4 acc[MT][2])
{
    const int col0 = 2 * w * 16 + (l & 15);
#pragma unroll
    for (int mt = 0; mt < MT; ++mt)
#pragma unroll
        for (int nti = 0; nti < 2; ++nti) {
            float bv = bias[col0 + nti * 16];
            acc[mt][nti][0] = bv; acc[mt][nti][1] = bv;
            acc[mt][nti][2] = bv; acc[mt][nti][3] = bv;
        }
#pragma unroll
    for (int kt = 0; kt < KT; ++kt) {
        uint4 ah[MT], al[MT];
#pragma unroll
        for (int mt = 0; mt < MT; ++mt) {
            ah[mt] = ldsA(Ah, mt * 16 + (l & 15), kt, l);
            al[mt] = ldsA(Al, mt * 16 + (l & 15), kt, l);
        }
#pragma unroll
        for (int nti = 0; nti < 2; ++nti) {
            const int nt = 2 * w + nti;
            uint4 bh = *(const uint4*)&wph[((nt * KT + kt) * 64 + l) * 8];
            uint4 bl = *(const uint4*)&wpl[((nt * KT + kt) * 64 + l) * 8];
#pragma unroll
            for (int mt = 0; mt < MT; ++mt) {
                acc[mt][nti] = mfma16(ah[mt], bh, acc[mt][nti]);
                acc[mt][nti] = mfma16(ah[mt], bl, acc[mt][nti]);
                acc[mt][nti] = mfma16(al[mt], bh, acc[mt][nti]);
            }
        }
    }
}

// ---------------------------------------------------------------------------
// Weight pre-pack: fragment-ordered bf16 hi/lo planes.
// ---------------------------------------------------------------------------
__global__ __launch_bounds__(256) void k_pack(
    const float* __restrict__ W2, const float* __restrict__ W3,
    const float* __restrict__ Wl, const float* __restrict__ P2,
    const float* __restrict__ P1, u16* __restrict__ wpk)
{
    int e = blockIdx.x * 256 + threadIdx.x;
    if (e >= PK_TOT) return;
    const float* src; int local, KT;
    if (e < OFF_P1) {
        int m = e >> 14;
        src = (m == 0) ? W2 : (m == 1) ? W3 : (m == 2) ? Wl : P2;
        local = e & 16383; KT = 4;
    } else {
        src = P1; local = e - OFF_P1; KT = 8;
    }
    int j = local & 7, lane = (local >> 3) & 63, t = local >> 9;
    int kt = t % KT, nt = t / KT;
    int k = kt * 32 + ((lane >> 4) << 3) + j;
    int n = nt * 16 + (lane & 15);
    float v = src[k * HD + n];
    u16 h = f2bf(v);
    wpk[e] = h;
    wpk[PK_TOT + e] = f2bf(v - bf2f(h));
}

// ---------------------------------------------------------------------------
// layer1 (16 -> 128) VALU fp32, output as hi/lo bf16 into U. NPH nodes/thread.
// ---------------------------------------------------------------------------
template<int NPH>
__device__ __forceinline__ void layer1(const float xs[][16],
                                       const float* __restrict__ W1,
                                       const float* __restrict__ b1,
                                       u16* Uh, u16* Ul, int f, int g)
{
    float w[16];
#pragma unroll
    for (int j = 0; j < 16; ++j) w[j] = W1[j * HD + f];
    const float bb = b1[f];
#pragma unroll
    for (int nn = 0; nn < NPH; ++nn) {
        const int row = g * NPH + nn;
        const float4* h4 = (const float4*)xs[row];
        float4 h0 = h4[0], h1 = h4[1], h2 = h4[2], h3 = h4[3];
        float a = bb
            + h0.x * w[0] + h0.y * w[1] + h0.z * w[2] + h0.w * w[3]
            + h1.x * w[4] + h1.y * w[5] + h1.z * w[6] + h1.w * w[7]
            + h2.x * w[8] + h2.y * w[9] + h2.z * w[10] + h2.w * w[11]
            + h3.x * w[12] + h3.y * w[13] + h3.z * w[14] + h3.w * w[15];
        a = fmaxf(a, 0.f);
        u16 h = f2bf(a);
        const int idx = row * 128 + (f ^ ((row & 7) << 3));
        Uh[idx] = h;
        Ul[idx] = f2bf(a - bf2f(h));
    }
}

// ---------------------------------------------------------------------------
// K1: mlp_pre + lin -> msg16[N,128] (bf16).  32 nodes / 256-thread block.
// ---------------------------------------------------------------------------
__global__ __launch_bounds__(256) void k_msg(
    const float* __restrict__ x,
    const float* __restrict__ W1, const float* __restrict__ b1,
    const float* __restrict__ b2, const float* __restrict__ b3,
    const float* __restrict__ bl,
    const u16* __restrict__ wpk, u16* __restrict__ msg16)
{
    __shared__ float xs[32][16];
    __shared__ __align__(16) u16 Uh[4096], Ul[4096], Vh[4096], Vl[4096];
    const int tid = threadIdx.x;
    const int l = tid & 63, w = tid >> 6;
    const int base = blockIdx.x * 32;

    for (int i = tid; i < 32 * 16; i += 256)
        xs[i >> 4][i & 15] = x[(base + (i >> 4)) * 16 + (i & 15)];
    __syncthreads();

    layer1<16>(xs, W1, b1, Uh, Ul, tid & 127, tid >> 7);
    __syncthreads();

    f32x4 acc[2][2];
    // W2: U -> V
    mfmaLayer<2, 4>(Uh, Ul, wpk + OFF_W2, wpk + PK_TOT + OFF_W2, b2, w, l, acc);
#pragma unroll
    for (int mt = 0; mt < 2; ++mt)
#pragma unroll
        for (int nti = 0; nti < 2; ++nti) writeAct(Vh, Vl, acc[mt][nti], mt, 2 * w + nti, l);
    __syncthreads();

    // W3: V -> U
    mfmaLayer<2, 4>(Vh, Vl, wpk + OFF_W3, wpk + PK_TOT + OFF_W3, b3, w, l, acc);
#pragma unroll
    for (int mt = 0; mt < 2; ++mt)
#pragma unroll
        for (int nti = 0; nti < 2; ++nti) writeAct(Uh, Ul, acc[mt][nti], mt, 2 * w + nti, l);
    __syncthreads();

    // lin: U -> V (hi plane = bf16(msg))
    mfmaLayer<2, 4>(Uh, Ul, wpk + OFF_WL, wpk + PK_TOT + OFF_WL, bl, w, l, acc);
#pragma unroll
    for (int mt = 0; mt < 2; ++mt)
#pragma unroll
        for (int nti = 0; nti < 2; ++nti) writeAct(Vh, Vl, acc[mt][nti], mt, 2 * w + nti, l);
    __syncthreads();

    // coalesced copy of hi plane -> msg16 (contiguous dwordx4 stores)
#pragma unroll
    for (int chunk = 0; chunk < 2; ++chunk) {
        int e = tid * 8 + chunk * 2048;
        int r = e >> 7, c0 = e & 127;
        uint4 v = *(const uint4*)&Vh[r * HD + (c0 ^ ((r & 7) << 3))];
        *(uint4*)&msg16[(size_t)(base + r) * HD + c0] = v;
    }
}

// ---------------------------------------------------------------------------
// CSR build (unchanged)
// ---------------------------------------------------------------------------
__global__ void k_hist(const int* __restrict__ dst, int* __restrict__ deg)
{
    int e = blockIdx.x * 256 + threadIdx.x;
    if (e < E_) atomicAdd(&deg[dst[e]], 1);
}

__global__ void k_bsum(const int* __restrict__ deg, int* __restrict__ part)
{
    __shared__ int s[256];
    int i = blockIdx.x * 256 + threadIdx.x;
    int t = threadIdx.x;
    s[t] = (i < N_) ? deg[i] : 0;
    __syncthreads();
    for (int st = 128; st > 0; st >>= 1) {
        if (t < st) s[t] += s[t + st];
        __syncthreads();
    }
    if (t == 0) part[blockIdx.x] = s[0];
}

__global__ void k_pscan(const int* __restrict__ part, int* __restrict__ poff, int nb)
{
    __shared__ int s[512];
    int t = threadIdx.x;
    int d = (t < nb) ? part[t] : 0;
    s[t] = d;
    __syncthreads();
    for (int st = 1; st < 512; st <<= 1) {
        int v = (t >= st) ? s[t - st] : 0;
        __syncthreads();
        s[t] += v;
        __syncthreads();
    }
    if (t < nb) poff[t] = s[t] - d;
}

__global__ void k_scan(const int* __restrict__ deg, const int* __restrict__ poff,
                       int* __restrict__ offs, int* __restrict__ cursor)
{
    __shared__ int s[256];
    int i = blockIdx.x * 256 + threadIdx.x;
    int t = threadIdx.x;
    int d = (i < N_) ? deg[i] : 0;
    s[t] = d;
    __syncthreads();
    for (int st = 1; st < 256; st <<= 1) {
        int v = (t >= st) ? s[t - st] : 0;
        __syncthreads();
        s[t] += v;
        __syncthreads();
    }
    if (i < N_) {
        int ex = s[t] - d + poff[blockIdx.x];
        offs[i] = ex;
        cursor[i] = ex;
    }
}

__global__ void k_fill(const int* __restrict__ src, const int* __restrict__ dst,
                       int* __restrict__ cursor, int* __restrict__ csr)
{
    int e = blockIdx.x * 256 + threadIdx.x;
    if (e < E_) {
        int pos = atomicAdd(&cursor[dst[e]], 1);
        csr[pos] = src[e];
    }
}

// ---------------------------------------------------------------------------
// K2b: dedicated gather kernel. One wave per node; lane l owns one u32
// (bf16 cols 2l, 2l+1) of the 256 B msg row -> 1 load/lane/edge, unroll x4.
// No LDS, minimal VGPR -> max occupancy & memory-level parallelism.
// Output agg16[N,128] bf16.
// ---------------------------------------------------------------------------
__global__ __launch_bounds__(256) void k_agg(
    const u16* __restrict__ msg16, const int* __restrict__ csr,
    const int* __restrict__ offs, const int* __restrict__ endp,
    u32* __restrict__ agg16)
{
    const int w = threadIdx.x >> 6, l = threadIdx.x & 63;
    const int node = blockIdx.x * 4 + w;
    if (node >= N_) return;
    const int s = offs[node], e = endp[node];
    float a0 = 0.f, a1 = 0.f;
    int i = s;
    for (; i + 4 <= e; i += 4) {
        int c0 = csr[i], c1 = csr[i + 1], c2 = csr[i + 2], c3 = csr[i + 3];
        u32 d0 = ((const u32*)(msg16 + (size_t)c0 * HD))[l];
        u32 d1 = ((const u32*)(msg16 + (size_t)c1 * HD))[l];
        u32 d2 = ((const u32*)(msg16 + (size_t)c2 * HD))[l];
        u32 d3 = ((const u32*)(msg16 + (size_t)c3 * HD))[l];
        a0 += (__uint_as_float(d0 << 16) + __uint_as_float(d1 << 16))
            + (__uint_as_float(d2 << 16) + __uint_as_float(d3 << 16));
        a1 += (__uint_as_float(d0 & 0xffff0000u) + __uint_as_float(d1 & 0xffff0000u))
            + (__uint_as_float(d2 & 0xffff0000u) + __uint_as_float(d3 & 0xffff0000u));
    }
    for (; i < e; ++i) {
        u32 d = ((const u32*)(msg16 + (size_t)csr[i] * HD))[l];
        a0 += __uint_as_float(d << 16);
        a1 += __uint_as_float(d & 0xffff0000u);
    }
    agg16[(size_t)node * 64 + l] = ((u32)f2bf(a1) << 16) | (u32)f2bf(a0);
}

// ---------------------------------------------------------------------------
// K3: recompute pre (MFMA) + mlp_post (MFMA) -> out. Gather removed (k_agg).
// 16 nodes / 256-thread block; LDS 17.4 KB. No min-waves hint: (256,8) and
// (256,4) both caused scratch spills (1.09 GB / 306 MB WRITE_SIZE).
// ---------------------------------------------------------------------------
__global__ __launch_bounds__(256) void k_post(
    const float* __restrict__ x, const u32* __restrict__ agg16,
    const float* __restrict__ W1, const float* __restrict__ b1,
    const float* __restrict__ b2, const float* __restrict__ b3,
    const float* __restrict__ pb1, const float* __restrict__ pb2,
    const float* __restrict__ P3, const float* __restrict__ pb3,
    const u16* __restrict__ wpk, float* __restrict__ out)
{
    __shared__ float xs[16][16];
    __shared__ __align__(16) u16 Uh[2048], Ul[2048], Vh[2048], Vl[2048];
    const int tid = threadIdx.x;
    const int l = tid & 63, w = tid >> 6;
    const int base = blockIdx.x * 16;

    xs[tid >> 4][tid & 15] = x[(base + (tid >> 4)) * 16 + (tid & 15)];
    __syncthreads();

    layer1<8>(xs, W1, b1, Uh, Ul, tid & 127, tid >> 7);
    __syncthreads();

    f32x4 acc[1][2];
    // W2: U -> V (h2)
    mfmaLayer<1, 4>(Uh, Ul, wpk + OFF_W2, wpk + PK_TOT + OFF_W2, b2, w, l, acc);
#pragma unroll
    for (int nti = 0; nti < 2; ++nti) writeAct(Vh, Vl, acc[0][nti], 0, 2 * w + nti, l);
    __syncthreads();

    // W3: V -> U (pre)
    mfmaLayer<1, 4>(Vh, Vl, wpk + OFF_W3, wpk + PK_TOT + OFF_W3, b3, w, l, acc);
#pragma unroll
    for (int nti = 0; nti < 2; ++nti) writeAct(Uh, Ul, acc[0][nti], 0, 2 * w + nti, l);
    __syncthreads();   // U = pre; V free

    // ---- load agg (bf16 global, coalesced uint4) -> V; lo plane is 0 ----
    {
        const int i0 = tid * 8;                 // 256 threads x 8 elems = 16x128
        const int row = i0 >> 7, c0 = i0 & 127;
        uint4 v = *(const uint4*)&agg16[((size_t)(base + row) * HD + c0) >> 1];
        const int idx = row * HD + (c0 ^ ((row & 7) << 3));
        *(uint4*)&Vh[idx] = v;
        *(uint4*)&Vl[idx] = uint4{0u, 0u, 0u, 0u};
    }
    __syncthreads();   // V = agg

    // P1: K=256 -> kt 0-3 read U (pre), kt 4-7 read V (agg)
    {
        const int col0 = 2 * w * 16 + (l & 15);
#pragma unroll
        for (int nti = 0; nti < 2; ++nti) {
            float bv = pb1[col0 + nti * 16];
            acc[0][nti][0] = bv; acc[0][nti][1] = bv;
            acc[0][nti][2] = bv; acc[0][nti][3] = bv;
        }
#pragma unroll
        for (int kt = 0; kt < 8; ++kt) {
            const u16* sh = (kt < 4) ? Uh : Vh;
            const u16* sl = (kt < 4) ? Ul : Vl;
            uint4 ah = ldsA(sh, l & 15, kt & 3, l);
            uint4 al = ldsA(sl, l & 15, kt & 3, l);
#pragma unroll
            for (int nti = 0; nti < 2; ++nti) {
                const int nt = 2 * w + nti;
                uint4 bh = *(const uint4*)&wpk[OFF_P1 + ((nt * 8 + kt) * 64 + l) * 8];
                uint4 bl = *(const uint4*)&wpk[PK_TOT + OFF_P1 + ((nt * 8 + kt) * 64 + l) * 8];
                acc[0][nti] = mfma16(ah, bh, acc[0][nti]);
                acc[0][nti] = mfma16(ah, bl, acc[0][nti]);
                acc[0][nti] = mfma16(al, bh, acc[0][nti]);
            }
        }
    }
    __syncthreads();   // all reads of U,V done
#pragma unroll
    for (int nti = 0; nti < 2; ++nti) writeAct(Uh, Ul, acc[0][nti], 0, 2 * w + nti, l);
    __syncthreads();

    // P2: U -> V (hi/lo, ReLU'd)
    mfmaLayer<1, 4>(Uh, Ul, wpk + OFF_P2, wpk + PK_TOT + OFF_P2, pb2, w, l, acc);
#pragma unroll
    for (int nti = 0; nti < 2; ++nti) writeAct(Vh, Vl, acc[0][nti], 0, 2 * w + nti, l);
    __syncthreads();

    // P3: 128 -> 16 + outer ReLU (VALU fp32, reads V hi+lo)
    {
        const int o = tid & 15;
        const int n = tid >> 4;
        const int sn = (n & 7) << 3;
        float a = pb3[o];
        for (int k0 = 0; k0 < HD; k0 += 8) {
            uint4 ph = *(const uint4*)&Vh[n * HD + (k0 ^ sn)];
            uint4 pl = *(const uint4*)&Vl[n * HD + (k0 ^ sn)];
            const u32 pw[4] = {ph.x, ph.y, ph.z, ph.w};
            const u32 qw[4] = {pl.x, pl.y, pl.z, pl.w};
#pragma unroll
            for (int j = 0; j < 8; ++j) {
                u32 hv = (j & 1) ? (pw[j >> 1] & 0xffff0000u) : (pw[j >> 1] << 16);
                u32 lv = (j & 1) ? (qw[j >> 1] & 0xffff0000u) : (qw[j >> 1] << 16);
                float hval = __uint_as_float(hv) + __uint_as_float(lv);
                a += hval * P3[(k0 + j) * 16 + o];
            }
        }
        out[(size_t)(base + n) * 16 + o] = fmaxf(a, 0.f);
    }
}

// ---------------------------------------------------------------------------
extern "C" void kernel_launch(void* const* d_in, const int* in_sizes, int n_in,
                              void* d_out, int out_size, void* d_ws, size_t ws_size,
                              hipStream_t stream)
{
    const float* x  = (const float*)d_in[0];
    const int*   ei = (const int*)d_in[1];
    const float* W1 = (const float*)d_in[2];  const float* b1  = (const float*)d_in[3];
    const float* W2 = (const float*)d_in[4];  const float* b2  = (const float*)d_in[5];
    const float* W3 = (const float*)d_in[6];  const float* b3  = (const float*)d_in[7];
    const float* Wl = (const float*)d_in[8];  const float* bl  = (const float*)d_in[9];
    const float* P1 = (const float*)d_in[10]; const float* pb1 = (const float*)d_in[11];
    const float* P2 = (const float*)d_in[12]; const float* pb2 = (const float*)d_in[13];
    const float* P3 = (const float*)d_in[14]; const float* pb3 = (const float*)d_in[15];
    float* out = (float*)d_out;

    // Workspace: msg16 25.6 + agg16 25.6 + csr 6.4 + ints 1.2 + wpk 0.4 ~= 59.2 MB
    char* ws = (char*)d_ws;
    u16* msg16  = (u16*)ws;   ws += (size_t)N_ * HD * 2;
    u32* agg16  = (u32*)ws;   ws += (size_t)N_ * 64 * 4;
    int* csr    = (int*)ws;   ws += (size_t)E_ * 4;
    int* deg    = (int*)ws;   ws += (size_t)N_ * 4;
    int* offs   = (int*)ws;   ws += (size_t)N_ * 4;
    int* cursor = (int*)ws;   ws += (size_t)N_ * 4;
    int* part   = (int*)ws;   ws += 512 * 4;
    int* poff   = (int*)ws;   ws += 512 * 4;
    u16* wpk    = (u16*)ws;   ws += (size_t)2 * PK_TOT * 2;

    const int* srcv = ei;
    const int* dstv = ei + E_;

    const int nbN = (N_ + 255) / 256;   // 391
    const int nbE = (E_ + 255) / 256;

    hipMemsetAsync(deg, 0, (size_t)N_ * 4, stream);
    k_pack<<<(PK_TOT + 255) / 256, 256, 0, stream>>>(W2, W3, Wl, P2, P1, wpk);
    k_msg<<<N_ / 32, 256, 0, stream>>>(x, W1, b1, b2, b3, bl, wpk, msg16);
    k_hist<<<nbE, 256, 0, stream>>>(dstv, deg);
    k_bsum<<<nbN, 256, 0, stream>>>(deg, part);
    k_pscan<<<1, 512, 0, stream>>>(part, poff, nbN);
    k_scan<<<nbN, 256, 0, stream>>>(deg, poff, offs, cursor);
    k_fill<<<nbE, 256, 0, stream>>>(srcv, dstv, cursor, csr);
    k_agg<<<(N_ + 3) / 4, 256, 0, stream>>>(msg16, csr, offs, cursor, agg16);
    k_post<<<N_ / 16, 256, 0, stream>>>(x, agg16,
                                        W1, b1, b2, b3, pb1, pb2, P3, pb3,
                                        wpk, out);
}

// Round 7
// 430.454 us; speedup vs baseline: 2.1221x; 1.1111x over previous
//
#include <hip/hip_runtime.h>

#define N_ 100000
#define E_ 1600000
#define HD 128

typedef unsigned short u16;
typedef unsigned int u32;
typedef __bf16 bf16x8 __attribute__((ext_vector_type(8)));
typedef float f32x4 __attribute__((ext_vector_type(4)));

// packed-weight element counts / offsets (in u16 elements)
#define OFF_W2 0
#define OFF_W3 16384
#define OFF_WL 32768
#define OFF_P2 49152
#define OFF_P1 65536
#define PK_TOT 98304   // hi plane size; lo plane at +PK_TOT

__device__ __forceinline__ u16 f2bf(float f) {
    u32 u = __float_as_uint(f);
    return (u16)((u + 0x7FFFu + ((u >> 16) & 1u)) >> 16);
}
__device__ __forceinline__ float bf2f(u16 h) {
    return __uint_as_float(((u32)h) << 16);
}
__device__ __forceinline__ f32x4 mfma16(uint4 a, uint4 b, f32x4 c) {
    return __builtin_amdgcn_mfma_f32_16x16x32_bf16(
        __builtin_bit_cast(bf16x8, a), __builtin_bit_cast(bf16x8, b), c, 0, 0, 0);
}

// Activation LDS layout (u16 array, [rows][128]): idx = row*128 + (col ^ ((row&7)<<3))
// A-fragment (mfma_f32_16x16x32_bf16): lane l holds A[row=l&15][k=8*(l>>4)+j], j=0..7
__device__ __forceinline__ uint4 ldsA(const u16* A, int row, int kt, int l) {
    int idx = row * 128 + (((kt * 32 + ((l >> 4) << 3))) ^ ((row & 7) << 3));
    return *(const uint4*)&A[idx];
}

// write C fragment (col=l&15 (+16*nt), row=4*(l>>4)+r (+16*mt)) as ReLU'd hi/lo bf16
__device__ __forceinline__ void writeAct(u16* Ah, u16* Al, f32x4 acc, int mt, int nt, int l) {
    const int col = nt * 16 + (l & 15);
#pragma unroll
    for (int r = 0; r < 4; ++r) {
        const int row = mt * 16 + ((l >> 4) << 2) + r;
        float a = fmaxf(acc[r], 0.f);
        u16 h = f2bf(a);
        const int idx = row * 128 + (col ^ ((row & 7) << 3));
        Ah[idx] = h;
        Al[idx] = f2bf(a - bf2f(h));
    }
}

// One MFMA layer: C[MT*16 x 128] = relu-pending( A[MT*16 x KT*32] @ W + bias )
// Wave w owns n-tiles 2w, 2w+1. hi/lo split: C += Ah*Bh + Ah*Bl + Al*Bh.
template<int MT, int KT>
__device__ __forceinline__ void mfmaLayer(const u16* Ah, const u16* Al,
                                          const u16* __restrict__ wph,
                                          const u16* __restrict__ wpl,
                                          const float* __restrict__ bias,
                                          int w, int l, f32x4 acc[MT][2])
{
    const int col0 = 2 * w * 16 + (l & 15);
#pragma unroll
    for (int mt = 0; mt < MT; ++mt)
#pragma unroll
        for (int nti = 0; nti < 2; ++nti) {
            float bv = bias[col0 + nti * 16];
            acc[mt][nti][0] = bv; acc[mt][nti][1] = bv;
            acc[mt][nti][2] = bv; acc[mt][nti][3] = bv;
        }
#pragma unroll
    for (int kt = 0; kt < KT; ++kt) {
        uint4 ah[MT], al[MT];
#pragma unroll
        for (int mt = 0; mt < MT; ++mt) {
            ah[mt] = ldsA(Ah, mt * 16 + (l & 15), kt, l);
            al[mt] = ldsA(Al, mt * 16 + (l & 15), kt, l);
        }
#pragma unroll
        for (int nti = 0; nti < 2; ++nti) {
            const int nt = 2 * w + nti;
            uint4 bh = *(const uint4*)&wph[((nt * KT + kt) * 64 + l) * 8];
            uint4 bl = *(const uint4*)&wpl[((nt * KT + kt) * 64 + l) * 8];
#pragma unroll
            for (int mt = 0; mt < MT; ++mt) {
                acc[mt][nti] = mfma16(ah[mt], bh, acc[mt][nti]);
                acc[mt][nti] = mfma16(ah[mt], bl, acc[mt][nti]);
                acc[mt][nti] = mfma16(al[mt], bh, acc[mt][nti]);
            }
        }
    }
}

// ---------------------------------------------------------------------------
// Weight pre-pack: fragment-ordered bf16 hi/lo planes.
// ---------------------------------------------------------------------------
__global__ __launch_bounds__(256) void k_pack(
    const float* __restrict__ W2, const float* __restrict__ W3,
    const float* __restrict__ Wl, const float* __restrict__ P2,
    const float* __restrict__ P1, u16* __restrict__ wpk)
{
    int e = blockIdx.x * 256 + threadIdx.x;
    if (e >= PK_TOT) return;
    const float* src; int local, KT;
    if (e < OFF_P1) {
        int m = e >> 14;
        src = (m == 0) ? W2 : (m == 1) ? W3 : (m == 2) ? Wl : P2;
        local = e & 16383; KT = 4;
    } else {
        src = P1; local = e - OFF_P1; KT = 8;
    }
    int j = local & 7, lane = (local >> 3) & 63, t = local >> 9;
    int kt = t % KT, nt = t / KT;
    int k = kt * 32 + ((lane >> 4) << 3) + j;
    int n = nt * 16 + (lane & 15);
    float v = src[k * HD + n];
    u16 h = f2bf(v);
    wpk[e] = h;
    wpk[PK_TOT + e] = f2bf(v - bf2f(h));
}

// ---------------------------------------------------------------------------
// layer1 (16 -> 128) VALU fp32, output as hi/lo bf16 into U. NPH nodes/thread.
// ---------------------------------------------------------------------------
template<int NPH>
__device__ __forceinline__ void layer1(const float xs[][16],
                                       const float* __restrict__ W1,
                                       const float* __restrict__ b1,
                                       u16* Uh, u16* Ul, int f, int g)
{
    float w[16];
#pragma unroll
    for (int j = 0; j < 16; ++j) w[j] = W1[j * HD + f];
    const float bb = b1[f];
#pragma unroll
    for (int nn = 0; nn < NPH; ++nn) {
        const int row = g * NPH + nn;
        const float4* h4 = (const float4*)xs[row];
        float4 h0 = h4[0], h1 = h4[1], h2 = h4[2], h3 = h4[3];
        float a = bb
            + h0.x * w[0] + h0.y * w[1] + h0.z * w[2] + h0.w * w[3]
            + h1.x * w[4] + h1.y * w[5] + h1.z * w[6] + h1.w * w[7]
            + h2.x * w[8] + h2.y * w[9] + h2.z * w[10] + h2.w * w[11]
            + h3.x * w[12] + h3.y * w[13] + h3.z * w[14] + h3.w * w[15];
        a = fmaxf(a, 0.f);
        u16 h = f2bf(a);
        const int idx = row * 128 + (f ^ ((row & 7) << 3));
        Uh[idx] = h;
        Ul[idx] = f2bf(a - bf2f(h));
    }
}

// ---------------------------------------------------------------------------
// K1: mlp_pre + lin -> msg16[N,128] (bf16), optionally pre hi/lo planes.
// 32 nodes / 256-thread block.
// ---------------------------------------------------------------------------
__global__ __launch_bounds__(256) void k_msg(
    const float* __restrict__ x,
    const float* __restrict__ W1, const float* __restrict__ b1,
    const float* __restrict__ b2, const float* __restrict__ b3,
    const float* __restrict__ bl,
    const u16* __restrict__ wpk, u16* __restrict__ msg16,
    u16* __restrict__ pre_h, u16* __restrict__ pre_l)
{
    __shared__ float xs[32][16];
    __shared__ __align__(16) u16 Uh[4096], Ul[4096], Vh[4096], Vl[4096];
    const int tid = threadIdx.x;
    const int l = tid & 63, w = tid >> 6;
    const int base = blockIdx.x * 32;

    for (int i = tid; i < 32 * 16; i += 256)
        xs[i >> 4][i & 15] = x[(base + (i >> 4)) * 16 + (i & 15)];
    __syncthreads();

    layer1<16>(xs, W1, b1, Uh, Ul, tid & 127, tid >> 7);
    __syncthreads();

    f32x4 acc[2][2];
    // W2: U -> V
    mfmaLayer<2, 4>(Uh, Ul, wpk + OFF_W2, wpk + PK_TOT + OFF_W2, b2, w, l, acc);
#pragma unroll
    for (int mt = 0; mt < 2; ++mt)
#pragma unroll
        for (int nti = 0; nti < 2; ++nti) writeAct(Vh, Vl, acc[mt][nti], mt, 2 * w + nti, l);
    __syncthreads();

    // W3: V -> U  (U = pre hi/lo)
    mfmaLayer<2, 4>(Vh, Vl, wpk + OFF_W3, wpk + PK_TOT + OFF_W3, b3, w, l, acc);
#pragma unroll
    for (int mt = 0; mt < 2; ++mt)
#pragma unroll
        for (int nti = 0; nti < 2; ++nti) writeAct(Uh, Ul, acc[mt][nti], mt, 2 * w + nti, l);
    __syncthreads();

    // lin: U -> V (hi plane = bf16(msg))
    mfmaLayer<2, 4>(Uh, Ul, wpk + OFF_WL, wpk + PK_TOT + OFF_WL, bl, w, l, acc);
#pragma unroll
    for (int mt = 0; mt < 2; ++mt)
#pragma unroll
        for (int nti = 0; nti < 2; ++nti) writeAct(Vh, Vl, acc[mt][nti], mt, 2 * w + nti, l);
    __syncthreads();

    // coalesced copies (contiguous dwordx4 stores): msg hi, pre hi/lo
#pragma unroll
    for (int chunk = 0; chunk < 2; ++chunk) {
        int e = tid * 8 + chunk * 2048;
        int r = e >> 7, c0 = e & 127;
        int idx = r * HD + (c0 ^ ((r & 7) << 3));
        size_t g = (size_t)(base + r) * HD + c0;
        *(uint4*)&msg16[g] = *(const uint4*)&Vh[idx];
        if (pre_h) {
            *(uint4*)&pre_h[g] = *(const uint4*)&Uh[idx];
            *(uint4*)&pre_l[g] = *(const uint4*)&Ul[idx];
        }
    }
}

// ---------------------------------------------------------------------------
// CSR build (unchanged)
// ---------------------------------------------------------------------------
__global__ void k_hist(const int* __restrict__ dst, int* __restrict__ deg)
{
    int e = blockIdx.x * 256 + threadIdx.x;
    if (e < E_) atomicAdd(&deg[dst[e]], 1);
}

__global__ void k_bsum(const int* __restrict__ deg, int* __restrict__ part)
{
    __shared__ int s[256];
    int i = blockIdx.x * 256 + threadIdx.x;
    int t = threadIdx.x;
    s[t] = (i < N_) ? deg[i] : 0;
    __syncthreads();
    for (int st = 128; st > 0; st >>= 1) {
        if (t < st) s[t] += s[t + st];
        __syncthreads();
    }
    if (t == 0) part[blockIdx.x] = s[0];
}

__global__ void k_pscan(const int* __restrict__ part, int* __restrict__ poff, int nb)
{
    __shared__ int s[512];
    int t = threadIdx.x;
    int d = (t < nb) ? part[t] : 0;
    s[t] = d;
    __syncthreads();
    for (int st = 1; st < 512; st <<= 1) {
        int v = (t >= st) ? s[t - st] : 0;
        __syncthreads();
        s[t] += v;
        __syncthreads();
    }
    if (t < nb) poff[t] = s[t] - d;
}

__global__ void k_scan(const int* __restrict__ deg, const int* __restrict__ poff,
                       int* __restrict__ offs, int* __restrict__ cursor)
{
    __shared__ int s[256];
    int i = blockIdx.x * 256 + threadIdx.x;
    int t = threadIdx.x;
    int d = (i < N_) ? deg[i] : 0;
    s[t] = d;
    __syncthreads();
    for (int st = 1; st < 256; st <<= 1) {
        int v = (t >= st) ? s[t - st] : 0;
        __syncthreads();
        s[t] += v;
        __syncthreads();
    }
    if (i < N_) {
        int ex = s[t] - d + poff[blockIdx.x];
        offs[i] = ex;
        cursor[i] = ex;
    }
}

__global__ void k_fill(const int* __restrict__ src, const int* __restrict__ dst,
                       int* __restrict__ cursor, int* __restrict__ csr)
{
    int e = blockIdx.x * 256 + threadIdx.x;
    if (e < E_) {
        int pos = atomicAdd(&cursor[dst[e]], 1);
        csr[pos] = src[e];
    }
}

// ---------------------------------------------------------------------------
// K2b: dedicated gather. One wave/node; lane l owns one u32 (2 bf16 cols).
// Unroll x8 for 8 independent loads in flight (deg ~16 avg).
// ---------------------------------------------------------------------------
__global__ __launch_bounds__(256) void k_agg(
    const u16* __restrict__ msg16, const int* __restrict__ csr,
    const int* __restrict__ offs, const int* __restrict__ endp,
    u32* __restrict__ agg16)
{
    const int w = threadIdx.x >> 6, l = threadIdx.x & 63;
    const int node = blockIdx.x * 4 + w;
    if (node >= N_) return;
    const int s = offs[node], e = endp[node];
    float a0 = 0.f, a1 = 0.f;
    int i = s;
    for (; i + 8 <= e; i += 8) {
        u32 d[8];
#pragma unroll
        for (int q = 0; q < 8; ++q)
            d[q] = ((const u32*)(msg16 + (size_t)csr[i + q] * HD))[l];
#pragma unroll
        for (int q = 0; q < 8; ++q) {
            a0 += __uint_as_float(d[q] << 16);
            a1 += __uint_as_float(d[q] & 0xffff0000u);
        }
    }
    for (; i < e; ++i) {
        u32 d = ((const u32*)(msg16 + (size_t)csr[i] * HD))[l];
        a0 += __uint_as_float(d << 16);
        a1 += __uint_as_float(d & 0xffff0000u);
    }
    agg16[(size_t)node * 64 + l] = ((u32)f2bf(a1) << 16) | (u32)f2bf(a0);
}

// ---------------------------------------------------------------------------
// K3a (pre path): load pre hi/lo + agg -> P1 -> P2 -> P3.
// 32 nodes / 256-thread block; LDS 32 KB; no recompute, ~5 barriers.
// ---------------------------------------------------------------------------
__global__ __launch_bounds__(256) void k_post_pre(
    const u16* __restrict__ pre_h, const u16* __restrict__ pre_l,
    const u32* __restrict__ agg16,
    const float* __restrict__ pb1, const float* __restrict__ pb2,
    const float* __restrict__ P3, const float* __restrict__ pb3,
    const u16* __restrict__ wpk, float* __restrict__ out)
{
    __shared__ __align__(16) u16 Uh[4096], Ul[4096], Vh[4096], Vl[4096];
    const int tid = threadIdx.x;
    const int l = tid & 63, w = tid >> 6;
    const int base = blockIdx.x * 32;

    // load pre planes -> U, agg -> V (lo = 0); swizzled LDS writes
#pragma unroll
    for (int chunk = 0; chunk < 2; ++chunk) {
        int e = tid * 8 + chunk * 2048;
        int r = e >> 7, c0 = e & 127;
        int idx = r * HD + (c0 ^ ((r & 7) << 3));
        size_t g = (size_t)(base + r) * HD + c0;
        *(uint4*)&Uh[idx] = *(const uint4*)&pre_h[g];
        *(uint4*)&Ul[idx] = *(const uint4*)&pre_l[g];
        *(uint4*)&Vh[idx] = *(const uint4*)&agg16[g >> 1];
        *(uint4*)&Vl[idx] = uint4{0u, 0u, 0u, 0u};
    }
    __syncthreads();

    f32x4 acc[2][2];
    // P1: K=256 -> kt 0-3 read U (pre), kt 4-7 read V (agg)
    {
        const int col0 = 2 * w * 16 + (l & 15);
#pragma unroll
        for (int mt = 0; mt < 2; ++mt)
#pragma unroll
            for (int nti = 0; nti < 2; ++nti) {
                float bv = pb1[col0 + nti * 16];
                acc[mt][nti][0] = bv; acc[mt][nti][1] = bv;
                acc[mt][nti][2] = bv; acc[mt][nti][3] = bv;
            }
#pragma unroll
        for (int kt = 0; kt < 8; ++kt) {
            const u16* sh = (kt < 4) ? Uh : Vh;
            const u16* sl = (kt < 4) ? Ul : Vl;
            uint4 ah[2], al[2];
#pragma unroll
            for (int mt = 0; mt < 2; ++mt) {
                ah[mt] = ldsA(sh, mt * 16 + (l & 15), kt & 3, l);
                al[mt] = ldsA(sl, mt * 16 + (l & 15), kt & 3, l);
            }
#pragma unroll
            for (int nti = 0; nti < 2; ++nti) {
                const int nt = 2 * w + nti;
                uint4 bh = *(const uint4*)&wpk[OFF_P1 + ((nt * 8 + kt) * 64 + l) * 8];
                uint4 bl = *(const uint4*)&wpk[PK_TOT + OFF_P1 + ((nt * 8 + kt) * 64 + l) * 8];
#pragma unroll
                for (int mt = 0; mt < 2; ++mt) {
                    acc[mt][nti] = mfma16(ah[mt], bh, acc[mt][nti]);
                    acc[mt][nti] = mfma16(ah[mt], bl, acc[mt][nti]);
                    acc[mt][nti] = mfma16(al[mt], bh, acc[mt][nti]);
                }
            }
        }
    }
    __syncthreads();
#pragma unroll
    for (int mt = 0; mt < 2; ++mt)
#pragma unroll
        for (int nti = 0; nti < 2; ++nti) writeAct(Uh, Ul, acc[mt][nti], mt, 2 * w + nti, l);
    __syncthreads();

    // P2: U -> V (hi/lo, ReLU'd)
    mfmaLayer<2, 4>(Uh, Ul, wpk + OFF_P2, wpk + PK_TOT + OFF_P2, pb2, w, l, acc);
#pragma unroll
    for (int mt = 0; mt < 2; ++mt)
#pragma unroll
        for (int nti = 0; nti < 2; ++nti) writeAct(Vh, Vl, acc[mt][nti], mt, 2 * w + nti, l);
    __syncthreads();

    // P3: 128 -> 16 + outer ReLU (VALU fp32, reads V hi+lo); 32 nodes -> 2 passes
    {
        const int o = tid & 15;
#pragma unroll
        for (int p = 0; p < 2; ++p) {
            const int n = p * 16 + (tid >> 4);
            const int sn = (n & 7) << 3;
            float a = pb3[o];
            for (int k0 = 0; k0 < HD; k0 += 8) {
                uint4 ph = *(const uint4*)&Vh[n * HD + (k0 ^ sn)];
                uint4 pl = *(const uint4*)&Vl[n * HD + (k0 ^ sn)];
                const u32 pw[4] = {ph.x, ph.y, ph.z, ph.w};
                const u32 qw[4] = {pl.x, pl.y, pl.z, pl.w};
#pragma unroll
                for (int j = 0; j < 8; ++j) {
                    u32 hv = (j & 1) ? (pw[j >> 1] & 0xffff0000u) : (pw[j >> 1] << 16);
                    u32 lv = (j & 1) ? (qw[j >> 1] & 0xffff0000u) : (qw[j >> 1] << 16);
                    a += (__uint_as_float(hv) + __uint_as_float(lv)) * P3[(k0 + j) * 16 + o];
                }
            }
            out[(size_t)(base + n) * 16 + o] = fmaxf(a, 0.f);
        }
    }
}

// ---------------------------------------------------------------------------
// K3b (fallback, ws too small): round-6 recompute kernel, proven 184 us.
// ---------------------------------------------------------------------------
__global__ __launch_bounds__(256) void k_post_rec(
    const float* __restrict__ x, const u32* __restrict__ agg16,
    const float* __restrict__ W1, const float* __restrict__ b1,
    const float* __restrict__ b2, const float* __restrict__ b3,
    const float* __restrict__ pb1, const float* __restrict__ pb2,
    const float* __restrict__ P3, const float* __restrict__ pb3,
    const u16* __restrict__ wpk, float* __restrict__ out)
{
    __shared__ float xs[16][16];
    __shared__ __align__(16) u16 Uh[2048], Ul[2048], Vh[2048], Vl[2048];
    const int tid = threadIdx.x;
    const int l = tid & 63, w = tid >> 6;
    const int base = blockIdx.x * 16;

    xs[tid >> 4][tid & 15] = x[(base + (tid >> 4)) * 16 + (tid & 15)];
    __syncthreads();

    layer1<8>(xs, W1, b1, Uh, Ul, tid & 127, tid >> 7);
    __syncthreads();

    f32x4 acc[1][2];
    mfmaLayer<1, 4>(Uh, Ul, wpk + OFF_W2, wpk + PK_TOT + OFF_W2, b2, w, l, acc);
#pragma unroll
    for (int nti = 0; nti < 2; ++nti) writeAct(Vh, Vl, acc[0][nti], 0, 2 * w + nti, l);
    __syncthreads();

    mfmaLayer<1, 4>(Vh, Vl, wpk + OFF_W3, wpk + PK_TOT + OFF_W3, b3, w, l, acc);
#pragma unroll
    for (int nti = 0; nti < 2; ++nti) writeAct(Uh, Ul, acc[0][nti], 0, 2 * w + nti, l);
    __syncthreads();

    {
        const int i0 = tid * 8;
        const int row = i0 >> 7, c0 = i0 & 127;
        uint4 v = *(const uint4*)&agg16[((size_t)(base + row) * HD + c0) >> 1];
        const int idx = row * HD + (c0 ^ ((row & 7) << 3));
        *(uint4*)&Vh[idx] = v;
        *(uint4*)&Vl[idx] = uint4{0u, 0u, 0u, 0u};
    }
    __syncthreads();

    {
        const int col0 = 2 * w * 16 + (l & 15);
#pragma unroll
        for (int nti = 0; nti < 2; ++nti) {
            float bv = pb1[col0 + nti * 16];
            acc[0][nti][0] = bv; acc[0][nti][1] = bv;
            acc[0][nti][2] = bv; acc[0][nti][3] = bv;
        }
#pragma unroll
        for (int kt = 0; kt < 8; ++kt) {
            const u16* sh = (kt < 4) ? Uh : Vh;
            const u16* sl = (kt < 4) ? Ul : Vl;
            uint4 ah = ldsA(sh, l & 15, kt & 3, l);
            uint4 al = ldsA(sl, l & 15, kt & 3, l);
#pragma unroll
            for (int nti = 0; nti < 2; ++nti) {
                const int nt = 2 * w + nti;
                uint4 bh = *(const uint4*)&wpk[OFF_P1 + ((nt * 8 + kt) * 64 + l) * 8];
                uint4 bl = *(const uint4*)&wpk[PK_TOT + OFF_P1 + ((nt * 8 + kt) * 64 + l) * 8];
                acc[0][nti] = mfma16(ah, bh, acc[0][nti]);
                acc[0][nti] = mfma16(ah, bl, acc[0][nti]);
                acc[0][nti] = mfma16(al, bh, acc[0][nti]);
            }
        }
    }
    __syncthreads();
#pragma unroll
    for (int nti = 0; nti < 2; ++nti) writeAct(Uh, Ul, acc[0][nti], 0, 2 * w + nti, l);
    __syncthreads();

    mfmaLayer<1, 4>(Uh, Ul, wpk + OFF_P2, wpk + PK_TOT + OFF_P2, pb2, w, l, acc);
#pragma unroll
    for (int nti = 0; nti < 2; ++nti) writeAct(Vh, Vl, acc[0][nti], 0, 2 * w + nti, l);
    __syncthreads();

    {
        const int o = tid & 15;
        const int n = tid >> 4;
        const int sn = (n & 7) << 3;
        float a = pb3[o];
        for (int k0 = 0; k0 < HD; k0 += 8) {
            uint4 ph = *(const uint4*)&Vh[n * HD + (k0 ^ sn)];
            uint4 pl = *(const uint4*)&Vl[n * HD + (k0 ^ sn)];
            const u32 pw[4] = {ph.x, ph.y, ph.z, ph.w};
            const u32 qw[4] = {pl.x, pl.y, pl.z, pl.w};
#pragma unroll
            for (int j = 0; j < 8; ++j) {
                u32 hv = (j & 1) ? (pw[j >> 1] & 0xffff0000u) : (pw[j >> 1] << 16);
                u32 lv = (j & 1) ? (qw[j >> 1] & 0xffff0000u) : (qw[j >> 1] << 16);
                a += (__uint_as_float(hv) + __uint_as_float(lv)) * P3[(k0 + j) * 16 + o];
            }
        }
        out[(size_t)(base + n) * 16 + o] = fmaxf(a, 0.f);
    }
}

// ---------------------------------------------------------------------------
extern "C" void kernel_launch(void* const* d_in, const int* in_sizes, int n_in,
                              void* d_out, int out_size, void* d_ws, size_t ws_size,
                              hipStream_t stream)
{
    const float* x  = (const float*)d_in[0];
    const int*   ei = (const int*)d_in[1];
    const float* W1 = (const float*)d_in[2];  const float* b1  = (const float*)d_in[3];
    const float* W2 = (const float*)d_in[4];  const float* b2  = (const float*)d_in[5];
    const float* W3 = (const float*)d_in[6];  const float* b3  = (const float*)d_in[7];
    const float* Wl = (const float*)d_in[8];  const float* bl  = (const float*)d_in[9];
    const float* P1 = (const float*)d_in[10]; const float* pb1 = (const float*)d_in[11];
    const float* P2 = (const float*)d_in[12]; const float* pb2 = (const float*)d_in[13];
    const float* P3 = (const float*)d_in[14]; const float* pb3 = (const float*)d_in[15];
    float* out = (float*)d_out;

    // Base workspace: msg16 25.6 + agg16 25.6 + csr 6.4 + ints 1.2 + wpk 0.4 ~= 59.2 MB
    // Optional pre planes: +51.2 MB (gated on ws_size).
    char* ws = (char*)d_ws;
    u16* msg16  = (u16*)ws;   ws += (size_t)N_ * HD * 2;
    u32* agg16  = (u32*)ws;   ws += (size_t)N_ * 64 * 4;
    int* csr    = (int*)ws;   ws += (size_t)E_ * 4;
    int* deg    = (int*)ws;   ws += (size_t)N_ * 4;
    int* offs   = (int*)ws;   ws += (size_t)N_ * 4;
    int* cursor = (int*)ws;   ws += (size_t)N_ * 4;
    int* part   = (int*)ws;   ws += 512 * 4;
    int* poff   = (int*)ws;   ws += 512 * 4;
    u16* wpk    = (u16*)ws;   ws += (size_t)2 * PK_TOT * 2;
    u16* pre_h  = (u16*)ws;   ws += (size_t)N_ * HD * 2;
    u16* pre_l  = (u16*)ws;   ws += (size_t)N_ * HD * 2;
    const size_t need_pre = (size_t)(ws - (char*)d_ws);
    const bool use_pre = ws_size >= need_pre;

    const int* srcv = ei;
    const int* dstv = ei + E_;

    const int nbN = (N_ + 255) / 256;   // 391
    const int nbE = (E_ + 255) / 256;

    hipMemsetAsync(deg, 0, (size_t)N_ * 4, stream);
    k_pack<<<(PK_TOT + 255) / 256, 256, 0, stream>>>(W2, W3, Wl, P2, P1, wpk);
    k_msg<<<N_ / 32, 256, 0, stream>>>(x, W1, b1, b2, b3, bl, wpk, msg16,
                                       use_pre ? pre_h : nullptr,
                                       use_pre ? pre_l : nullptr);
    k_hist<<<nbE, 256, 0, stream>>>(dstv, deg);
    k_bsum<<<nbN, 256, 0, stream>>>(deg, part);
    k_pscan<<<1, 512, 0, stream>>>(part, poff, nbN);
    k_scan<<<nbN, 256, 0, stream>>>(deg, poff, offs, cursor);
    k_fill<<<nbE, 256, 0, stream>>>(srcv, dstv, cursor, csr);
    k_agg<<<(N_ + 3) / 4, 256, 0, stream>>>(msg16, csr, offs, cursor, agg16);
    if (use_pre) {
        k_post_pre<<<N_ / 32, 256, 0, stream>>>(pre_h, pre_l, agg16,
                                                pb1, pb2, P3, pb3, wpk, out);
    } else {
        k_post_rec<<<N_ / 16, 256, 0, stream>>>(x, agg16,
                                                W1, b1, b2, b3, pb1, pb2, P3, pb3,
                                                wpk, out);
    }
}

// Round 8
// 242.569 us; speedup vs baseline: 3.7657x; 1.7746x over previous
//
#include <hip/hip_runtime.h>

#define N_ 100000
#define E_ 1600000
#define HD 128
#define NB 391      // dst buckets of 256 nodes (391*256 = 100096 >= N_)
#define GB 256      // binning blocks
#define CHK 6250    // edges per binning block (256*6250 = 1.6M exact)
#define NBGB (NB * GB)

typedef unsigned short u16;
typedef unsigned int u32;
typedef __bf16 bf16x8 __attribute__((ext_vector_type(8)));
typedef float f32x4 __attribute__((ext_vector_type(4)));

// packed-weight offsets (u16 elements)
#define OFF_W2 0
#define OFF_W3 16384
#define OFF_WL 32768
#define OFF_P2 49152
#define OFF_P1 65536
#define PK_TOT 98304   // hi plane size; lo plane at +PK_TOT

__device__ __forceinline__ u16 f2bf(float f) {
    u32 u = __float_as_uint(f);
    return (u16)((u + 0x7FFFu + ((u >> 16) & 1u)) >> 16);
}
__device__ __forceinline__ float bf2f(u16 h) {
    return __uint_as_float(((u32)h) << 16);
}
__device__ __forceinline__ f32x4 mfma16(uint4 a, uint4 b, f32x4 c) {
    return __builtin_amdgcn_mfma_f32_16x16x32_bf16(
        __builtin_bit_cast(bf16x8, a), __builtin_bit_cast(bf16x8, b), c, 0, 0, 0);
}

// Activation LDS layout (u16, [rows][128]): idx = row*128 + (col ^ ((row&7)<<3))
__device__ __forceinline__ uint4 ldsA(const u16* A, int row, int kt, int l) {
    int idx = row * 128 + (((kt * 32 + ((l >> 4) << 3))) ^ ((row & 7) << 3));
    return *(const uint4*)&A[idx];
}

// write C fragment (col=16*nt+(l&15), row=16*mt+4*(l>>4)+r) as ReLU'd hi/lo bf16
__device__ __forceinline__ void writeAct(u16* Ah, u16* Al, f32x4 acc, int mt, int nt, int l) {
    const int col = nt * 16 + (l & 15);
#pragma unroll
    for (int r = 0; r < 4; ++r) {
        const int row = mt * 16 + ((l >> 4) << 2) + r;
        float a = fmaxf(acc[r], 0.f);
        u16 h = f2bf(a);
        const int idx = row * 128 + (col ^ ((row & 7) << 3));
        Ah[idx] = h;
        Al[idx] = f2bf(a - bf2f(h));
    }
}

// One MFMA layer slice: wave owns single n-tile nt. hi/lo 3-product.
template<int MT, int KT>
__device__ __forceinline__ void mfmaLayerW(const u16* Ah, const u16* Al,
                                           const u16* __restrict__ wph,
                                           const u16* __restrict__ wpl,
                                           const float* __restrict__ bias,
                                           int nt, int l, f32x4 acc[MT])
{
    const float bv = bias[nt * 16 + (l & 15)];
#pragma unroll
    for (int mt = 0; mt < MT; ++mt) {
        acc[mt][0] = bv; acc[mt][1] = bv; acc[mt][2] = bv; acc[mt][3] = bv;
    }
#pragma unroll
    for (int kt = 0; kt < KT; ++kt) {
        uint4 bh = *(const uint4*)&wph[((nt * KT + kt) * 64 + l) * 8];
        uint4 bl = *(const uint4*)&wpl[((nt * KT + kt) * 64 + l) * 8];
#pragma unroll
        for (int mt = 0; mt < MT; ++mt) {
            uint4 ah = ldsA(Ah, mt * 16 + (l & 15), kt, l);
            uint4 al = ldsA(Al, mt * 16 + (l & 15), kt, l);
            acc[mt] = mfma16(al, bh, acc[mt]);
            acc[mt] = mfma16(ah, bl, acc[mt]);
            acc[mt] = mfma16(ah, bh, acc[mt]);
        }
    }
}

// ---------------------------------------------------------------------------
// Weight pre-pack: fragment-ordered bf16 hi/lo planes.
// ---------------------------------------------------------------------------
__global__ __launch_bounds__(256) void k_pack(
    const float* __restrict__ W2, const float* __restrict__ W3,
    const float* __restrict__ Wl, const float* __restrict__ P2,
    const float* __restrict__ P1, u16* __restrict__ wpk)
{
    int e = blockIdx.x * 256 + threadIdx.x;
    if (e >= PK_TOT) return;
    const float* src; int local, KT;
    if (e < OFF_P1) {
        int m = e >> 14;
        src = (m == 0) ? W2 : (m == 1) ? W3 : (m == 2) ? Wl : P2;
        local = e & 16383; KT = 4;
    } else {
        src = P1; local = e - OFF_P1; KT = 8;
    }
    int j = local & 7, lane = (local >> 3) & 63, t = local >> 9;
    int kt = t % KT, nt = t / KT;
    int k = kt * 32 + ((lane >> 4) << 3) + j;
    int n = nt * 16 + (lane & 15);
    float v = src[k * HD + n];
    u16 h = f2bf(v);
    wpk[e] = h;
    wpk[PK_TOT + e] = f2bf(v - bf2f(h));
}

// ---------------------------------------------------------------------------
// layer1 (16 -> 128) VALU fp32 -> hi/lo bf16 LDS. 512 thr: g=tid>>7, NPH=8.
// ---------------------------------------------------------------------------
template<int NPH>
__device__ __forceinline__ void layer1(const float xs[][16],
                                       const float* __restrict__ W1,
                                       const float* __restrict__ b1,
                                       u16* Uh, u16* Ul, int f, int g)
{
    float w[16];
#pragma unroll
    for (int j = 0; j < 16; ++j) w[j] = W1[j * HD + f];
    const float bb = b1[f];
#pragma unroll
    for (int nn = 0; nn < NPH; ++nn) {
        const int row = g * NPH + nn;
        const float4* h4 = (const float4*)xs[row];
        float4 h0 = h4[0], h1 = h4[1], h2 = h4[2], h3 = h4[3];
        float a = bb
            + h0.x * w[0] + h0.y * w[1] + h0.z * w[2] + h0.w * w[3]
            + h1.x * w[4] + h1.y * w[5] + h1.z * w[6] + h1.w * w[7]
            + h2.x * w[8] + h2.y * w[9] + h2.z * w[10] + h2.w * w[11]
            + h3.x * w[12] + h3.y * w[13] + h3.z * w[14] + h3.w * w[15];
        a = fmaxf(a, 0.f);
        u16 h = f2bf(a);
        const int idx = row * 128 + (f ^ ((row & 7) << 3));
        Uh[idx] = h;
        Ul[idx] = f2bf(a - bf2f(h));
    }
}

// ---------------------------------------------------------------------------
// K1: mlp_pre + lin -> msg16 (bf16) + pre16 (bf16 hi only).
// 32 nodes / 512-thread block (8 waves, one n-tile each).
// ---------------------------------------------------------------------------
__global__ __launch_bounds__(512) void k_msg(
    const float* __restrict__ x,
    const float* __restrict__ W1, const float* __restrict__ b1,
    const float* __restrict__ b2, const float* __restrict__ b3,
    const float* __restrict__ blin,
    const u16* __restrict__ wpk, u16* __restrict__ msg16,
    u16* __restrict__ pre16)
{
    __shared__ float xs[32][16];
    __shared__ __align__(16) u16 Uh[4096], Ul[4096], Vh[4096], Vl[4096];
    const int tid = threadIdx.x;
    const int l = tid & 63, w = tid >> 6;   // w in [0,8)
    const int base = blockIdx.x * 32;

    xs[tid >> 4][tid & 15] = x[(base + (tid >> 4)) * 16 + (tid & 15)];
    __syncthreads();

    layer1<8>(xs, W1, b1, Uh, Ul, tid & 127, tid >> 7);
    __syncthreads();

    f32x4 acc[2];
    // W2: U -> V
    mfmaLayerW<2, 4>(Uh, Ul, wpk + OFF_W2, wpk + PK_TOT + OFF_W2, b2, w, l, acc);
    writeAct(Vh, Vl, acc[0], 0, w, l);
    writeAct(Vh, Vl, acc[1], 1, w, l);
    __syncthreads();

    // W3: V -> U (U = pre)
    mfmaLayerW<2, 4>(Vh, Vl, wpk + OFF_W3, wpk + PK_TOT + OFF_W3, b3, w, l, acc);
    writeAct(Uh, Ul, acc[0], 0, w, l);
    writeAct(Uh, Ul, acc[1], 1, w, l);
    __syncthreads();

    // lin: U -> V (hi = bf16(msg))
    mfmaLayerW<2, 4>(Uh, Ul, wpk + OFF_WL, wpk + PK_TOT + OFF_WL, blin, w, l, acc);
    writeAct(Vh, Vl, acc[0], 0, w, l);
    writeAct(Vh, Vl, acc[1], 1, w, l);
    __syncthreads();

    // coalesced stores: msg = Vh, pre = Uh (single bf16 plane)
    {
        int e = tid * 8;
        int r = e >> 7, c0 = e & 127;
        int idx = r * HD + (c0 ^ ((r & 7) << 3));
        size_t g = (size_t)(base + r) * HD + c0;
        *(uint4*)&msg16[g] = *(const uint4*)&Vh[idx];
        *(uint4*)&pre16[g] = *(const uint4*)&Uh[idx];
    }
}

// ---------------------------------------------------------------------------
// CSR build, bucketed (dst>>8). Phase A: per-(bucket,block) LDS counts.
// ---------------------------------------------------------------------------
__global__ __launch_bounds__(256) void k_count(const int* __restrict__ dst,
                                               int* __restrict__ cnt)
{
    __shared__ int lc[NB];
    const int tid = threadIdx.x;
    for (int i = tid; i < NB; i += 256) lc[i] = 0;
    __syncthreads();
    const int e0 = blockIdx.x * CHK, e1 = min(e0 + CHK, E_);
    for (int e = e0 + tid; e < e1; e += 256)
        atomicAdd(&lc[dst[e] >> 8], 1);
    __syncthreads();
    for (int i = tid; i < NB; i += 256) cnt[i * GB + blockIdx.x] = lc[i];
}

// generalized block-sum / scan helpers
__global__ void k_bsum(const int* __restrict__ v, int* __restrict__ part, int L)
{
    __shared__ int s[256];
    int i = blockIdx.x * 256 + threadIdx.x;
    int t = threadIdx.x;
    s[t] = (i < L) ? v[i] : 0;
    __syncthreads();
    for (int st = 128; st > 0; st >>= 1) {
        if (t < st) s[t] += s[t + st];
        __syncthreads();
    }
    if (t == 0) part[blockIdx.x] = s[0];
}

__global__ void k_pscan(const int* __restrict__ part, int* __restrict__ poff, int nb)
{
    __shared__ int s[512];
    int t = threadIdx.x;
    int d = (t < nb) ? part[t] : 0;
    s[t] = d;
    __syncthreads();
    for (int st = 1; st < 512; st <<= 1) {
        int v = (t >= st) ? s[t - st] : 0;
        __syncthreads();
        s[t] += v;
        __syncthreads();
    }
    if (t < nb) poff[t] = s[t] - d;
}

__global__ void k_scan_excl(const int* __restrict__ v, const int* __restrict__ poff,
                            int* __restrict__ outp, int L)
{
    __shared__ int s[256];
    int i = blockIdx.x * 256 + threadIdx.x;
    int t = threadIdx.x;
    int d = (i < L) ? v[i] : 0;
    s[t] = d;
    __syncthreads();
    for (int st = 1; st < 256; st <<= 1) {
        int vv = (t >= st) ? s[t - st] : 0;
        __syncthreads();
        s[t] += vv;
        __syncthreads();
    }
    if (i < L) outp[i] = s[t] - d + poff[blockIdx.x];
}

// Phase C: scatter edges into bucket-ordered ebuf (uint2{src,dst}).
__global__ __launch_bounds__(256) void k_scatter(const int* __restrict__ src,
                                                 const int* __restrict__ dst,
                                                 const int* __restrict__ escan,
                                                 uint2* __restrict__ ebuf)
{
    __shared__ int lcur[NB];
    const int tid = threadIdx.x;
    for (int i = tid; i < NB; i += 256) lcur[i] = escan[i * GB + blockIdx.x];
    __syncthreads();
    const int e0 = blockIdx.x * CHK, e1 = min(e0 + CHK, E_);
    for (int e = e0 + tid; e < e1; e += 256) {
        int s = src[e], d = dst[e];
        int pos = atomicAdd(&lcur[d >> 8], 1);
        ebuf[pos] = uint2{(u32)s, (u32)d};
    }
}

// Phase D: per-bucket node offsets (LDS hist+scan) + csr fill. One block/bucket.
__global__ __launch_bounds__(256) void k_fill2(const uint2* __restrict__ ebuf,
                                               const int* __restrict__ escan,
                                               int* __restrict__ offs,
                                               int* __restrict__ endp,
                                               int* __restrict__ csr)
{
    __shared__ int hist[256], sc[256], cur[256];
    const int tid = threadIdx.x, b = blockIdx.x;
    const int s = escan[b * GB];
    const int e = (b == NB - 1) ? E_ : escan[(b + 1) * GB];
    hist[tid] = 0;
    __syncthreads();
    for (int i = s + tid; i < e; i += 256)
        atomicAdd(&hist[ebuf[i].y & 255], 1);
    __syncthreads();
    int d = hist[tid];
    sc[tid] = d;
    __syncthreads();
    for (int st = 1; st < 256; st <<= 1) {
        int v = (tid >= st) ? sc[tid - st] : 0;
        __syncthreads();
        sc[tid] += v;
        __syncthreads();
    }
    int ex = s + sc[tid] - d;
    int node = (b << 8) + tid;
    if (node < N_) { offs[node] = ex; endp[node] = ex + d; }
    cur[tid] = ex;
    __syncthreads();
    for (int i = s + tid; i < e; i += 256) {
        uint2 u = ebuf[i];
        int pos = atomicAdd(&cur[u.y & 255], 1);
        csr[pos] = u.x;
    }
}

// ---------------------------------------------------------------------------
// K2b: gather. One wave/node; lane l owns one u32 (2 bf16 cols); unroll x8.
// ---------------------------------------------------------------------------
__global__ __launch_bounds__(256) void k_agg(
    const u16* __restrict__ msg16, const int* __restrict__ csr,
    const int* __restrict__ offs, const int* __restrict__ endp,
    u32* __restrict__ agg16)
{
    const int w = threadIdx.x >> 6, l = threadIdx.x & 63;
    const int node = blockIdx.x * 4 + w;
    if (node >= N_) return;
    const int s = offs[node], e = endp[node];
    float a0 = 0.f, a1 = 0.f;
    int i = s;
    for (; i + 8 <= e; i += 8) {
        u32 d[8];
#pragma unroll
        for (int q = 0; q < 8; ++q)
            d[q] = ((const u32*)(msg16 + (size_t)csr[i + q] * HD))[l];
#pragma unroll
        for (int q = 0; q < 8; ++q) {
            a0 += __uint_as_float(d[q] << 16);
            a1 += __uint_as_float(d[q] & 0xffff0000u);
        }
    }
    for (; i < e; ++i) {
        u32 d = ((const u32*)(msg16 + (size_t)csr[i] * HD))[l];
        a0 += __uint_as_float(d << 16);
        a1 += __uint_as_float(d & 0xffff0000u);
    }
    agg16[(size_t)node * 64 + l] = ((u32)f2bf(a1) << 16) | (u32)f2bf(a0);
}

// ---------------------------------------------------------------------------
// K3: pre16 + agg16 -> P1 (2-product, lo planes zero) -> P2 -> P3 -> out.
// 32 nodes / 512-thread block (8 waves, one n-tile each). LDS 32 KB.
// ---------------------------------------------------------------------------
__global__ __launch_bounds__(512) void k_post(
    const u16* __restrict__ pre16, const u32* __restrict__ agg16,
    const float* __restrict__ pb1, const float* __restrict__ pb2,
    const float* __restrict__ P3, const float* __restrict__ pb3,
    const u16* __restrict__ wpk, float* __restrict__ out)
{
    __shared__ __align__(16) u16 Uh[4096], Ul[4096], Vh[4096], Vl[4096];
    const int tid = threadIdx.x;
    const int l = tid & 63, w = tid >> 6;
    const int base = blockIdx.x * 32;

    // load pre -> Uh, agg -> Vh (both single-plane bf16)
    {
        int e = tid * 8;
        int r = e >> 7, c0 = e & 127;
        int idx = r * HD + (c0 ^ ((r & 7) << 3));
        size_t g = (size_t)(base + r) * HD + c0;
        *(uint4*)&Uh[idx] = *(const uint4*)&pre16[g];
        *(uint4*)&Vh[idx] = *(const uint4*)&agg16[g >> 1];
    }
    __syncthreads();

    f32x4 acc[2];
    // P1 (K=256): kt 0-3 from Uh (pre), kt 4-7 from Vh (agg); A-lo is zero
    {
        const float bv = pb1[w * 16 + (l & 15)];
        acc[0][0] = bv; acc[0][1] = bv; acc[0][2] = bv; acc[0][3] = bv;
        acc[1] = acc[0];
#pragma unroll
        for (int kt = 0; kt < 8; ++kt) {
            const u16* sh = (kt < 4) ? Uh : Vh;
            uint4 bh = *(const uint4*)&wpk[OFF_P1 + ((w * 8 + kt) * 64 + l) * 8];
            uint4 bl = *(const uint4*)&wpk[PK_TOT + OFF_P1 + ((w * 8 + kt) * 64 + l) * 8];
#pragma unroll
            for (int mt = 0; mt < 2; ++mt) {
                uint4 ah = ldsA(sh, mt * 16 + (l & 15), kt & 3, l);
                acc[mt] = mfma16(ah, bl, acc[mt]);
                acc[mt] = mfma16(ah, bh, acc[mt]);
            }
        }
    }
    __syncthreads();   // all P1 reads of Uh done before overwrite
    writeAct(Uh, Ul, acc[0], 0, w, l);
    writeAct(Uh, Ul, acc[1], 1, w, l);
    __syncthreads();

    // P2: U -> V (hi/lo, ReLU'd)
    mfmaLayerW<2, 4>(Uh, Ul, wpk + OFF_P2, wpk + PK_TOT + OFF_P2, pb2, w, l, acc);
    writeAct(Vh, Vl, acc[0], 0, w, l);
    writeAct(Vh, Vl, acc[1], 1, w, l);
    __syncthreads();

    // P3: 128 -> 16 + outer ReLU (VALU fp32; 512 thr = 32 nodes x 16 outs)
    {
        const int o = tid & 15;
        const int n = tid >> 4;
        const int sn = (n & 7) << 3;
        float a = pb3[o];
        for (int k0 = 0; k0 < HD; k0 += 8) {
            uint4 ph = *(const uint4*)&Vh[n * HD + (k0 ^ sn)];
            uint4 pl = *(const uint4*)&Vl[n * HD + (k0 ^ sn)];
            const u32 pw[4] = {ph.x, ph.y, ph.z, ph.w};
            const u32 qw[4] = {pl.x, pl.y, pl.z, pl.w};
#pragma unroll
            for (int j = 0; j < 8; ++j) {
                u32 hv = (j & 1) ? (pw[j >> 1] & 0xffff0000u) : (pw[j >> 1] << 16);
                u32 lv = (j & 1) ? (qw[j >> 1] & 0xffff0000u) : (qw[j >> 1] << 16);
                a += (__uint_as_float(hv) + __uint_as_float(lv)) * P3[(k0 + j) * 16 + o];
            }
        }
        out[(size_t)(base + n) * 16 + o] = fmaxf(a, 0.f);
    }
}

// ---------------------------------------------------------------------------
extern "C" void kernel_launch(void* const* d_in, const int* in_sizes, int n_in,
                              void* d_out, int out_size, void* d_ws, size_t ws_size,
                              hipStream_t stream)
{
    const float* x  = (const float*)d_in[0];
    const int*   ei = (const int*)d_in[1];
    const float* W1 = (const float*)d_in[2];  const float* b1  = (const float*)d_in[3];
    const float* W2 = (const float*)d_in[4];  const float* b2  = (const float*)d_in[5];
    const float* W3 = (const float*)d_in[6];  const float* b3  = (const float*)d_in[7];
    const float* Wl = (const float*)d_in[8];  const float* bl  = (const float*)d_in[9];
    const float* P1 = (const float*)d_in[10]; const float* pb1 = (const float*)d_in[11];
    const float* P2 = (const float*)d_in[12]; const float* pb2 = (const float*)d_in[13];
    const float* P3 = (const float*)d_in[14]; const float* pb3 = (const float*)d_in[15];
    float* out = (float*)d_out;

    // Workspace ~85.8 MB total (<= the >=110.4 MB confirmed in round 7):
    // msg16 25.6 | agg16 25.6 (ebuf 12.8 aliased inside, dead before k_agg)
    // csr 6.4 | offs .4 | endp .4 | cnt .4 | escan .4 | partC/poffC | wpk .4 | pre16 25.6
    char* ws = (char*)d_ws;
    u16* msg16  = (u16*)ws;   ws += (size_t)N_ * HD * 2;
    u32* agg16  = (u32*)ws;   ws += (size_t)N_ * 64 * 4;
    uint2* ebuf = (uint2*)agg16;                     // alias: dead before k_agg writes
    int* csr    = (int*)ws;   ws += (size_t)E_ * 4;
    int* offs   = (int*)ws;   ws += (size_t)N_ * 4;
    int* endp   = (int*)ws;   ws += (size_t)N_ * 4;
    int* cnt    = (int*)ws;   ws += (size_t)NBGB * 4;
    int* escan  = (int*)ws;   ws += (size_t)NBGB * 4;
    int* partC  = (int*)ws;   ws += 512 * 4;
    int* poffC  = (int*)ws;   ws += 512 * 4;
    u16* wpk    = (u16*)ws;   ws += (size_t)2 * PK_TOT * 2;
    u16* pre16  = (u16*)ws;   ws += (size_t)N_ * HD * 2;

    const int* srcv = ei;
    const int* dstv = ei + E_;
    const int nbC = NBGB / 256;   // 391 (exact)

    k_pack<<<(PK_TOT + 255) / 256, 256, 0, stream>>>(W2, W3, Wl, P2, P1, wpk);
    k_msg<<<N_ / 32, 512, 0, stream>>>(x, W1, b1, b2, b3, bl, wpk, msg16, pre16);
    k_count<<<GB, 256, 0, stream>>>(dstv, cnt);
    k_bsum<<<nbC, 256, 0, stream>>>(cnt, partC, NBGB);
    k_pscan<<<1, 512, 0, stream>>>(partC, poffC, nbC);
    k_scan_excl<<<nbC, 256, 0, stream>>>(cnt, poffC, escan, NBGB);
    k_scatter<<<GB, 256, 0, stream>>>(srcv, dstv, escan, ebuf);
    k_fill2<<<NB, 256, 0, stream>>>(ebuf, escan, offs, endp, csr);
    k_agg<<<(N_ + 3) / 4, 256, 0, stream>>>(msg16, csr, offs, endp, agg16);
    k_post<<<N_ / 32, 512, 0, stream>>>(pre16, agg16, pb1, pb2, P3, pb3, wpk, out);
}

// Round 9
// 213.133 us; speedup vs baseline: 4.2858x; 1.1381x over previous
//
#include <hip/hip_runtime.h>

#define N_ 100000
#define E_ 1600000
#define HD 128
#define NB 391      // dst buckets of 256 nodes (391*256 = 100096 >= N_)
#define GB 256      // binning blocks
#define CHK 6250    // edges per binning block (256*6250 = 1.6M exact)
#define NBGB (NB * GB)

typedef unsigned short u16;
typedef unsigned int u32;
typedef __bf16 bf16x8 __attribute__((ext_vector_type(8)));
typedef float f32x4 __attribute__((ext_vector_type(4)));

// packed-weight offsets (u16 elements)
#define OFF_W2 0
#define OFF_W3 16384
#define OFF_WL 32768
#define OFF_P2 49152
#define OFF_P1 65536
#define PK_TOT 98304   // hi plane size; lo plane at +PK_TOT

__device__ __forceinline__ u16 f2bf(float f) {
    u32 u = __float_as_uint(f);
    return (u16)((u + 0x7FFFu + ((u >> 16) & 1u)) >> 16);
}
__device__ __forceinline__ float bf2f(u16 h) {
    return __uint_as_float(((u32)h) << 16);
}
__device__ __forceinline__ f32x4 mfma16(uint4 a, uint4 b, f32x4 c) {
    return __builtin_amdgcn_mfma_f32_16x16x32_bf16(
        __builtin_bit_cast(bf16x8, a), __builtin_bit_cast(bf16x8, b), c, 0, 0, 0);
}

// Activation LDS layout (u16, [rows][128]): idx = row*128 + (col ^ ((row&7)<<3))
__device__ __forceinline__ uint4 ldsA(const u16* A, int row, int kt, int l) {
    int idx = row * 128 + (((kt * 32 + ((l >> 4) << 3))) ^ ((row & 7) << 3));
    return *(const uint4*)&A[idx];
}

// write C fragment (col=16*nt+(l&15), row=16*mt+4*(l>>4)+r) as ReLU'd bf16 (hi only)
__device__ __forceinline__ void writeActH(u16* Ah, f32x4 acc, int mt, int nt, int l) {
    const int col = nt * 16 + (l & 15);
#pragma unroll
    for (int r = 0; r < 4; ++r) {
        const int row = mt * 16 + ((l >> 4) << 2) + r;
        Ah[row * 128 + (col ^ ((row & 7) << 3))] = f2bf(fmaxf(acc[r], 0.f));
    }
}

// One MFMA layer slice: wave owns n-tile nt. Weights hi/lo 2-product, act hi only.
template<int MT, int KT>
__device__ __forceinline__ void mfmaLayerW(const u16* Ah,
                                           const u16* __restrict__ wph,
                                           const u16* __restrict__ wpl,
                                           const float* __restrict__ bias,
                                           int nt, int l, f32x4 acc[MT])
{
    const float bv = bias[nt * 16 + (l & 15)];
#pragma unroll
    for (int mt = 0; mt < MT; ++mt) {
        acc[mt][0] = bv; acc[mt][1] = bv; acc[mt][2] = bv; acc[mt][3] = bv;
    }
#pragma unroll
    for (int kt = 0; kt < KT; ++kt) {
        uint4 bh = *(const uint4*)&wph[((nt * KT + kt) * 64 + l) * 8];
        uint4 bl = *(const uint4*)&wpl[((nt * KT + kt) * 64 + l) * 8];
#pragma unroll
        for (int mt = 0; mt < MT; ++mt) {
            uint4 ah = ldsA(Ah, mt * 16 + (l & 15), kt, l);
            acc[mt] = mfma16(ah, bl, acc[mt]);
            acc[mt] = mfma16(ah, bh, acc[mt]);
        }
    }
}

// ---------------------------------------------------------------------------
// Weight pre-pack: fragment-ordered bf16 hi/lo planes.
// ---------------------------------------------------------------------------
__global__ __launch_bounds__(256) void k_pack(
    const float* __restrict__ W2, const float* __restrict__ W3,
    const float* __restrict__ Wl, const float* __restrict__ P2,
    const float* __restrict__ P1, u16* __restrict__ wpk)
{
    int e = blockIdx.x * 256 + threadIdx.x;
    if (e >= PK_TOT) return;
    const float* src; int local, KT;
    if (e < OFF_P1) {
        int m = e >> 14;
        src = (m == 0) ? W2 : (m == 1) ? W3 : (m == 2) ? Wl : P2;
        local = e & 16383; KT = 4;
    } else {
        src = P1; local = e - OFF_P1; KT = 8;
    }
    int j = local & 7, lane = (local >> 3) & 63, t = local >> 9;
    int kt = t % KT, nt = t / KT;
    int k = kt * 32 + ((lane >> 4) << 3) + j;
    int n = nt * 16 + (lane & 15);
    float v = src[k * HD + n];
    u16 h = f2bf(v);
    wpk[e] = h;
    wpk[PK_TOT + e] = f2bf(v - bf2f(h));
}

// ---------------------------------------------------------------------------
// layer1 (16 -> 128) VALU fp32 -> bf16 LDS (hi only). 512 thr: g=tid>>7, NPH=8.
// ---------------------------------------------------------------------------
template<int NPH>
__device__ __forceinline__ void layer1(const float xs[][16],
                                       const float* __restrict__ W1,
                                       const float* __restrict__ b1,
                                       u16* Uh, int f, int g)
{
    float w[16];
#pragma unroll
    for (int j = 0; j < 16; ++j) w[j] = W1[j * HD + f];
    const float bb = b1[f];
#pragma unroll
    for (int nn = 0; nn < NPH; ++nn) {
        const int row = g * NPH + nn;
        const float4* h4 = (const float4*)xs[row];
        float4 h0 = h4[0], h1 = h4[1], h2 = h4[2], h3 = h4[3];
        float a = bb
            + h0.x * w[0] + h0.y * w[1] + h0.z * w[2] + h0.w * w[3]
            + h1.x * w[4] + h1.y * w[5] + h1.z * w[6] + h1.w * w[7]
            + h2.x * w[8] + h2.y * w[9] + h2.z * w[10] + h2.w * w[11]
            + h3.x * w[12] + h3.y * w[13] + h3.z * w[14] + h3.w * w[15];
        Uh[row * 128 + (f ^ ((row & 7) << 3))] = f2bf(fmaxf(a, 0.f));
    }
}

// ---------------------------------------------------------------------------
// K1: mlp_pre + lin -> msg16 (bf16) + pre16 (bf16).
// 32 nodes / 512-thread block (8 waves, one n-tile each). LDS 18 KB.
// ---------------------------------------------------------------------------
__global__ __launch_bounds__(512) void k_msg(
    const float* __restrict__ x,
    const float* __restrict__ W1, const float* __restrict__ b1,
    const float* __restrict__ b2, const float* __restrict__ b3,
    const float* __restrict__ blin,
    const u16* __restrict__ wpk, u16* __restrict__ msg16,
    u16* __restrict__ pre16)
{
    __shared__ float xs[32][16];
    __shared__ __align__(16) u16 Uh[4096], Vh[4096];
    const int tid = threadIdx.x;
    const int l = tid & 63, w = tid >> 6;   // w in [0,8)
    const int base = blockIdx.x * 32;

    xs[tid >> 4][tid & 15] = x[(base + (tid >> 4)) * 16 + (tid & 15)];
    __syncthreads();

    layer1<8>(xs, W1, b1, Uh, tid & 127, tid >> 7);
    __syncthreads();

    f32x4 acc[2];
    // W2: U -> V
    mfmaLayerW<2, 4>(Uh, wpk + OFF_W2, wpk + PK_TOT + OFF_W2, b2, w, l, acc);
    writeActH(Vh, acc[0], 0, w, l);
    writeActH(Vh, acc[1], 1, w, l);
    __syncthreads();

    // W3: V -> U (U = pre)
    mfmaLayerW<2, 4>(Vh, wpk + OFF_W3, wpk + PK_TOT + OFF_W3, b3, w, l, acc);
    writeActH(Uh, acc[0], 0, w, l);
    writeActH(Uh, acc[1], 1, w, l);
    __syncthreads();

    // lin: U -> V (bf16 msg)
    mfmaLayerW<2, 4>(Uh, wpk + OFF_WL, wpk + PK_TOT + OFF_WL, blin, w, l, acc);
    writeActH(Vh, acc[0], 0, w, l);
    writeActH(Vh, acc[1], 1, w, l);
    __syncthreads();

    // coalesced stores: msg = Vh, pre = Uh
    {
        int e = tid * 8;
        int r = e >> 7, c0 = e & 127;
        int idx = r * HD + (c0 ^ ((r & 7) << 3));
        size_t g = (size_t)(base + r) * HD + c0;
        *(uint4*)&msg16[g] = *(const uint4*)&Vh[idx];
        *(uint4*)&pre16[g] = *(const uint4*)&Uh[idx];
    }
}

// ---------------------------------------------------------------------------
// CSR build, bucketed (dst>>8). Phase A: per-(bucket,block) LDS counts.
// ---------------------------------------------------------------------------
__global__ __launch_bounds__(256) void k_count(const int* __restrict__ dst,
                                               int* __restrict__ cnt)
{
    __shared__ int lc[NB];
    const int tid = threadIdx.x;
    for (int i = tid; i < NB; i += 256) lc[i] = 0;
    __syncthreads();
    const int e0 = blockIdx.x * CHK, e1 = min(e0 + CHK, E_);
    for (int e = e0 + tid; e < e1; e += 256)
        atomicAdd(&lc[dst[e] >> 8], 1);
    __syncthreads();
    for (int i = tid; i < NB; i += 256) cnt[i * GB + blockIdx.x] = lc[i];
}

__global__ void k_bsum(const int* __restrict__ v, int* __restrict__ part, int L)
{
    __shared__ int s[256];
    int i = blockIdx.x * 256 + threadIdx.x;
    int t = threadIdx.x;
    s[t] = (i < L) ? v[i] : 0;
    __syncthreads();
    for (int st = 128; st > 0; st >>= 1) {
        if (t < st) s[t] += s[t + st];
        __syncthreads();
    }
    if (t == 0) part[blockIdx.x] = s[0];
}

__global__ void k_pscan(const int* __restrict__ part, int* __restrict__ poff, int nb)
{
    __shared__ int s[512];
    int t = threadIdx.x;
    int d = (t < nb) ? part[t] : 0;
    s[t] = d;
    __syncthreads();
    for (int st = 1; st < 512; st <<= 1) {
        int v = (t >= st) ? s[t - st] : 0;
        __syncthreads();
        s[t] += v;
        __syncthreads();
    }
    if (t < nb) poff[t] = s[t] - d;
}

__global__ void k_scan_excl(const int* __restrict__ v, const int* __restrict__ poff,
                            int* __restrict__ outp, int L)
{
    __shared__ int s[256];
    int i = blockIdx.x * 256 + threadIdx.x;
    int t = threadIdx.x;
    int d = (i < L) ? v[i] : 0;
    s[t] = d;
    __syncthreads();
    for (int st = 1; st < 256; st <<= 1) {
        int vv = (t >= st) ? s[t - st] : 0;
        __syncthreads();
        s[t] += vv;
        __syncthreads();
    }
    if (i < L) outp[i] = s[t] - d + poff[blockIdx.x];
}

// Phase C: scatter edges into bucket-ordered ebuf (uint2{src,dst}).
__global__ __launch_bounds__(256) void k_scatter(const int* __restrict__ src,
                                                 const int* __restrict__ dst,
                                                 const int* __restrict__ escan,
                                                 uint2* __restrict__ ebuf)
{
    __shared__ int lcur[NB];
    const int tid = threadIdx.x;
    for (int i = tid; i < NB; i += 256) lcur[i] = escan[i * GB + blockIdx.x];
    __syncthreads();
    const int e0 = blockIdx.x * CHK, e1 = min(e0 + CHK, E_);
    for (int e = e0 + tid; e < e1; e += 256) {
        int s = src[e], d = dst[e];
        int pos = atomicAdd(&lcur[d >> 8], 1);
        ebuf[pos] = uint2{(u32)s, (u32)d};
    }
}

// Phase D: per-bucket node offsets (LDS hist+scan) + csr fill. One block/bucket.
__global__ __launch_bounds__(256) void k_fill2(const uint2* __restrict__ ebuf,
                                               const int* __restrict__ escan,
                                               int* __restrict__ offs,
                                               int* __restrict__ endp,
                                               int* __restrict__ csr)
{
    __shared__ int hist[256], sc[256], cur[256];
    const int tid = threadIdx.x, b = blockIdx.x;
    const int s = escan[b * GB];
    const int e = (b == NB - 1) ? E_ : escan[(b + 1) * GB];
    hist[tid] = 0;
    __syncthreads();
    for (int i = s + tid; i < e; i += 256)
        atomicAdd(&hist[ebuf[i].y & 255], 1);
    __syncthreads();
    int d = hist[tid];
    sc[tid] = d;
    __syncthreads();
    for (int st = 1; st < 256; st <<= 1) {
        int v = (tid >= st) ? sc[tid - st] : 0;
        __syncthreads();
        sc[tid] += v;
        __syncthreads();
    }
    int ex = s + sc[tid] - d;
    int node = (b << 8) + tid;
    if (node < N_) { offs[node] = ex; endp[node] = ex + d; }
    cur[tid] = ex;
    __syncthreads();
    for (int i = s + tid; i < e; i += 256) {
        uint2 u = ebuf[i];
        int pos = atomicAdd(&cur[u.y & 255], 1);
        csr[pos] = u.x;
    }
}

// ---------------------------------------------------------------------------
// K2b: gather. One wave/node; lane l owns one u32 (2 bf16 cols); unroll x8.
// ---------------------------------------------------------------------------
__global__ __launch_bounds__(256) void k_agg(
    const u16* __restrict__ msg16, const int* __restrict__ csr,
    const int* __restrict__ offs, const int* __restrict__ endp,
    u32* __restrict__ agg16)
{
    const int w = threadIdx.x >> 6, l = threadIdx.x & 63;
    const int node = blockIdx.x * 4 + w;
    if (node >= N_) return;
    const int s = offs[node], e = endp[node];
    float a0 = 0.f, a1 = 0.f;
    int i = s;
    for (; i + 8 <= e; i += 8) {
        u32 d[8];
#pragma unroll
        for (int q = 0; q < 8; ++q)
            d[q] = ((const u32*)(msg16 + (size_t)csr[i + q] * HD))[l];
#pragma unroll
        for (int q = 0; q < 8; ++q) {
            a0 += __uint_as_float(d[q] << 16);
            a1 += __uint_as_float(d[q] & 0xffff0000u);
        }
    }
    for (; i < e; ++i) {
        u32 d = ((const u32*)(msg16 + (size_t)csr[i] * HD))[l];
        a0 += __uint_as_float(d << 16);
        a1 += __uint_as_float(d & 0xffff0000u);
    }
    agg16[(size_t)node * 64 + l] = ((u32)f2bf(a1) << 16) | (u32)f2bf(a0);
}

// ---------------------------------------------------------------------------
// K3: pre16 + agg16 -> P1 -> P2 -> P3 -> out.
// 32 nodes / 512-thread block (8 waves, one n-tile each). LDS 16 KB.
// ---------------------------------------------------------------------------
__global__ __launch_bounds__(512) void k_post(
    const u16* __restrict__ pre16, const u32* __restrict__ agg16,
    const float* __restrict__ pb1, const float* __restrict__ pb2,
    const float* __restrict__ P3, const float* __restrict__ pb3,
    const u16* __restrict__ wpk, float* __restrict__ out)
{
    __shared__ __align__(16) u16 Uh[4096], Vh[4096];
    const int tid = threadIdx.x;
    const int l = tid & 63, w = tid >> 6;
    const int base = blockIdx.x * 32;

    // load pre -> Uh, agg -> Vh (both single-plane bf16)
    {
        int e = tid * 8;
        int r = e >> 7, c0 = e & 127;
        int idx = r * HD + (c0 ^ ((r & 7) << 3));
        size_t g = (size_t)(base + r) * HD + c0;
        *(uint4*)&Uh[idx] = *(const uint4*)&pre16[g];
        *(uint4*)&Vh[idx] = *(const uint4*)&agg16[g >> 1];
    }
    __syncthreads();

    f32x4 acc[2];
    // P1 (K=256): kt 0-3 from Uh (pre), kt 4-7 from Vh (agg)
    {
        const float bv = pb1[w * 16 + (l & 15)];
        acc[0][0] = bv; acc[0][1] = bv; acc[0][2] = bv; acc[0][3] = bv;
        acc[1] = acc[0];
#pragma unroll
        for (int kt = 0; kt < 8; ++kt) {
            const u16* sh = (kt < 4) ? Uh : Vh;
            uint4 bh = *(const uint4*)&wpk[OFF_P1 + ((w * 8 + kt) * 64 + l) * 8];
            uint4 bl = *(const uint4*)&wpk[PK_TOT + OFF_P1 + ((w * 8 + kt) * 64 + l) * 8];
#pragma unroll
            for (int mt = 0; mt < 2; ++mt) {
                uint4 ah = ldsA(sh, mt * 16 + (l & 15), kt & 3, l);
                acc[mt] = mfma16(ah, bl, acc[mt]);
                acc[mt] = mfma16(ah, bh, acc[mt]);
            }
        }
    }
    __syncthreads();   // all P1 reads of Uh done before overwrite
    writeActH(Uh, acc[0], 0, w, l);
    writeActH(Uh, acc[1], 1, w, l);
    __syncthreads();

    // P2: U -> V (bf16, ReLU'd)
    mfmaLayerW<2, 4>(Uh, wpk + OFF_P2, wpk + PK_TOT + OFF_P2, pb2, w, l, acc);
    writeActH(Vh, acc[0], 0, w, l);
    writeActH(Vh, acc[1], 1, w, l);
    __syncthreads();

    // P3: 128 -> 16 + outer ReLU (VALU fp32; 512 thr = 32 nodes x 16 outs)
    {
        const int o = tid & 15;
        const int n = tid >> 4;
        const int sn = (n & 7) << 3;
        float a = pb3[o];
        for (int k0 = 0; k0 < HD; k0 += 8) {
            uint4 ph = *(const uint4*)&Vh[n * HD + (k0 ^ sn)];
            const u32 pw[4] = {ph.x, ph.y, ph.z, ph.w};
#pragma unroll
            for (int j = 0; j < 8; ++j) {
                u32 hv = (j & 1) ? (pw[j >> 1] & 0xffff0000u) : (pw[j >> 1] << 16);
                a += __uint_as_float(hv) * P3[(k0 + j) * 16 + o];
            }
        }
        out[(size_t)(base + n) * 16 + o] = fmaxf(a, 0.f);
    }
}

// ---------------------------------------------------------------------------
extern "C" void kernel_launch(void* const* d_in, const int* in_sizes, int n_in,
                              void* d_out, int out_size, void* d_ws, size_t ws_size,
                              hipStream_t stream)
{
    const float* x  = (const float*)d_in[0];
    const int*   ei = (const int*)d_in[1];
    const float* W1 = (const float*)d_in[2];  const float* b1  = (const float*)d_in[3];
    const float* W2 = (const float*)d_in[4];  const float* b2  = (const float*)d_in[5];
    const float* W3 = (const float*)d_in[6];  const float* b3  = (const float*)d_in[7];
    const float* Wl = (const float*)d_in[8];  const float* bl  = (const float*)d_in[9];
    const float* P1 = (const float*)d_in[10]; const float* pb1 = (const float*)d_in[11];
    const float* P2 = (const float*)d_in[12]; const float* pb2 = (const float*)d_in[13];
    const float* P3 = (const float*)d_in[14]; const float* pb3 = (const float*)d_in[15];
    float* out = (float*)d_out;

    // Workspace ~85.8 MB total
    char* ws = (char*)d_ws;
    u16* msg16  = (u16*)ws;   ws += (size_t)N_ * HD * 2;
    u32* agg16  = (u32*)ws;   ws += (size_t)N_ * 64 * 4;
    uint2* ebuf = (uint2*)agg16;                     // alias: dead before k_agg writes
    int* csr    = (int*)ws;   ws += (size_t)E_ * 4;
    int* offs   = (int*)ws;   ws += (size_t)N_ * 4;
    int* endp   = (int*)ws;   ws += (size_t)N_ * 4;
    int* cnt    = (int*)ws;   ws += (size_t)NBGB * 4;
    int* escan  = (int*)ws;   ws += (size_t)NBGB * 4;
    int* partC  = (int*)ws;   ws += 512 * 4;
    int* poffC  = (int*)ws;   ws += 512 * 4;
    u16* wpk    = (u16*)ws;   ws += (size_t)2 * PK_TOT * 2;
    u16* pre16  = (u16*)ws;   ws += (size_t)N_ * HD * 2;

    const int* srcv = ei;
    const int* dstv = ei + E_;
    const int nbC = NBGB / 256;   // 391 (exact)

    k_pack<<<(PK_TOT + 255) / 256, 256, 0, stream>>>(W2, W3, Wl, P2, P1, wpk);
    k_msg<<<N_ / 32, 512, 0, stream>>>(x, W1, b1, b2, b3, bl, wpk, msg16, pre16);
    k_count<<<GB, 256, 0, stream>>>(dstv, cnt);
    k_bsum<<<nbC, 256, 0, stream>>>(cnt, partC, NBGB);
    k_pscan<<<1, 512, 0, stream>>>(partC, poffC, nbC);
    k_scan_excl<<<nbC, 256, 0, stream>>>(cnt, poffC, escan, NBGB);
    k_scatter<<<GB, 256, 0, stream>>>(srcv, dstv, escan, ebuf);
    k_fill2<<<NB, 256, 0, stream>>>(ebuf, escan, offs, endp, csr);
    k_agg<<<(N_ + 3) / 4, 256, 0, stream>>>(msg16, csr, offs, endp, agg16);
    k_post<<<N_ / 32, 512, 0, stream>>>(pre16, agg16, pb1, pb2, P3, pb3, wpk, out);
}